// Round 11
// baseline (377.880 us; speedup 1.0000x reference)
//
#include <hip/hip_runtime.h>
#include <cstddef>

#define NPIX 1024   // H*W = 32*32

// ---------------------------------------------------------------------------
// Workspace layout (float-slot offsets). Peak 34,045,952 floats (136 MB).
// ---------------------------------------------------------------------------
static constexpr size_t WQKV_OFF  = 0;          //  98304 floats (768x256 bf16)
static constexpr size_t WPROJ_OFF = 98304;      //  65536 (256x512)
static constexpr size_t WINV_OFF  = 163840;     // 131072 (1024x256)
static constexpr size_t WPW_OFF   = 294912;     // 131072 (256x1024)
static constexpr size_t XT_OFF    = 425984;     // 2097152 (16x256x1024 bf16 blocked)
static constexpr size_t QKV_OFF   = 2523136;    // 6291456 (16x768x1024 bf16 [c][n])
static constexpr size_t DPW_OFF   = 8814592;    // 6291456
static constexpr size_t ATT_OFF   = 15106048;   // 4194304 (16x512x1024 bf16 blocked)
static constexpr size_t KVP_OFF   = 19300352;   // 270336 (256x1056 fp32, final kv)
static constexpr size_t T1_OFF    = 21463040;   // 4194304 (16x256x1024 fp32 [c][n])
static constexpr size_t T1T_OFF   = 25657344;   // 2097152 (16x32x1024x8 bf16 blocked)
static constexpr size_t H1T_OFF   = 425984;     // 8388608 (16x128x1024x8 bf16 blocked)
static constexpr size_t H2T_OFF   = 25657344;   // 8388608 (blocked; overwrites t1t after inv)

typedef __attribute__((ext_vector_type(8))) short bf16x8;
typedef __attribute__((ext_vector_type(8))) unsigned short u16x8;
typedef __attribute__((ext_vector_type(4))) unsigned short u16x4;
typedef __attribute__((ext_vector_type(4))) float f32x4;

__device__ inline unsigned short f2bf(float f) {
    union { float f; unsigned int u; } v; v.f = f;
    unsigned int u = v.u;
    u += 0x7FFFu + ((u >> 16) & 1u);        // round-to-nearest-even
    return (unsigned short)(u >> 16);
}
__device__ inline float bf2f(unsigned short u) {
    union { float f; unsigned int u; } v; v.u = ((unsigned int)u) << 16;
    return v.f;
}
__device__ inline u16x8 zero8() {
    u16x8 z = {0, 0, 0, 0, 0, 0, 0, 0};
    return z;
}

#define GLOAD_LDS16(gp, lp) __builtin_amdgcn_global_load_lds(                  \
    (const __attribute__((address_space(1))) unsigned int*)(const void*)(gp), \
    (__attribute__((address_space(3))) unsigned int*)(void*)(lp), 16, 0, 0)

// ---------------------------------------------------------------------------
// Weight convert (all 4 weights in ONE launch): fp32 [O][K] -> bf16 [K/8][O][8]
// ---------------------------------------------------------------------------
__global__ __launch_bounds__(256)
void wconv_all(const float* __restrict__ w0, const float* __restrict__ w1,
               const float* __restrict__ w2, const float* __restrict__ w3,
               unsigned short* __restrict__ d0, unsigned short* __restrict__ d1,
               unsigned short* __restrict__ d2, unsigned short* __restrict__ d3)
{
    const int bid = blockIdx.x;
    const float* W; unsigned short* WB; int O, K, base;
    if (bid < 96)       { W = w0; WB = d0; O = 768;  K = 256;  base = 0;   }
    else if (bid < 160) { W = w1; WB = d1; O = 256;  K = 512;  base = 96;  }
    else if (bid < 288) { W = w2; WB = d2; O = 1024; K = 256;  base = 160; }
    else                { W = w3; WB = d3; O = 256;  K = 1024; base = 288; }
    const int idx = (bid - base) * 256 + threadIdx.x;
    if (idx >= O * (K >> 3)) return;
    const int o = idx % O;
    const int koct = idx / O;
    u16x8 v;
#pragma unroll
    for (int j = 0; j < 8; j++) v[j] = f2bf(W[(size_t)o * K + koct * 8 + j]);
    *(u16x8*)(WB + ((size_t)koct * O + o) * 8) = v;
}

// ---------------------------------------------------------------------------
// Transpose: fp32 [b][C][1024] -> blocked bf16 [b][C/8][1024][8]
// ---------------------------------------------------------------------------
__global__ __launch_bounds__(256)
void xpose_f32_bf16(const float* __restrict__ X, unsigned short* __restrict__ XT,
                    const int C)
{
    __shared__ float tt[8][260];
    const int t = threadIdx.x;
    const int octs = C >> 3;
    const int strips = octs * 4;
    const int b = blockIdx.x / strips;
    const int rem = blockIdx.x - b * strips;
    const int coct = rem >> 2;
    const int n0 = (rem & 3) * 256;

    const int cc = t >> 5;
    const int c8 = (t & 31) * 8;
    const float* xp = X + ((size_t)b * C + coct * 8 + cc) * NPIX + n0 + c8;
    *(float4*)(&tt[cc][c8])     = *(const float4*)(xp);
    *(float4*)(&tt[cc][c8 + 4]) = *(const float4*)(xp + 4);
    __syncthreads();
    u16x8 v;
#pragma unroll
    for (int j = 0; j < 8; j++) v[j] = f2bf(tt[j][t]);
    *(u16x8*)(XT + (((size_t)b * octs + coct) * NPIX + n0 + t) * 8) = v;
}

// ---------------------------------------------------------------------------
// MFMA GEMM, blocked-bf16 operands, BK=32 double-buffered (m97 structure):
//   X: [b][K/8][1024][8] bf16, W: [K/8][O][8] bf16;  Y = W·X (+ epilogue)
// Block tile BM x BN, 4 waves; BN=128: 2x2 waves (wave BM/2 x 64);
//                              BN=64:  4x1 waves (wave BM/4 x 64).
// LDS: [2][BM][32] + [2][BN][32] u16 (rows = 64B = 4 slots of 16B).
// Swizzle slot ^= (row & 3), folded into the GLOBAL k-oct on stage (linear
// LDS dest for global_load_lds) and applied on ds_read.
// EPI: 0 plain, 1 BN+residual(+ACC), 2 bias+hswish.
// OMODE: 0 fp32 [c][n]; 1 bf16 [c][n] (LDS-transposed); 2 blocked bf16;
//        3 fp32 [c][n] + blocked bf16 (dual)
// ---------------------------------------------------------------------------
template<int BM, int BN, int EPI, bool ACC, int OMODE>
__global__ __launch_bounds__(256)
void gemm_blk(const unsigned short* __restrict__ X, const unsigned short* __restrict__ W,
              float* __restrict__ Y, unsigned short* __restrict__ YB,
              const int O, const int K,
              const float* __restrict__ res,
              const float* __restrict__ bng, const float* __restrict__ bnb,
              const float* __restrict__ bnm, const float* __restrict__ bnv,
              const float* __restrict__ bias)
{
    constexpr int TN = NPIX / BN;               // n-tiles per image
    constexpr int WAVES_N = (BN >= 128) ? 2 : 1;
    constexpr int WM = BM / (4 / WAVES_N);
    constexpr int MI = WM / 16;
    constexpr int NJ = 4;                       // wave n-extent always 64
    constexpr int TSTR = (OMODE == 1) ? (BN + 8) : (BM + 8);
    constexpr int TSZ  = (OMODE == 1) ? BM * TSTR : (OMODE >= 2 ? BN * TSTR : 0);
    constexpr int BUFSZ = 2 * 32 * (BM + BN);
    constexpr int SM = (BUFSZ > TSZ) ? BUFSZ : TSZ;
    __shared__ unsigned short smem[SM];
    unsigned short* Asm = smem;                 // [2][BM][32]
    unsigned short* Bsm = smem + 2 * BM * 32;   // [2][BN][32]
    unsigned short* T   = smem;                 // epilogue transpose (aliases)

    const int t    = threadIdx.x;
    const int lane = t & 63;
    const int w    = t >> 6;

    // XCD-bijective block swizzle (all grids are multiples of 8)
    const int gx  = gridDim.x;
    const int nwg = gx * gridDim.y;
    int bid = blockIdx.y * gx + blockIdx.x;
    bid = (bid & 7) * (nwg >> 3) + (bid >> 3);
    const int bx = bid % gx;
    const int by = bid / gx;

    const int o0 = bx * BM;
    const int b  = by / TN;
    const int n0 = (by % TN) * BN;

    const int wn = (WAVES_N == 2) ? (w & 1) * 64 : 0;
    const int wo = (WAVES_N == 2) ? (w >> 1) * WM : w * WM;

    f32x4 acc[MI][NJ];
#pragma unroll
    for (int i = 0; i < MI; i++)
#pragma unroll
        for (int j = 0; j < NJ; j++) {
            f32x4 z = {0.f, 0.f, 0.f, 0.f};
            acc[i][j] = z;
        }

    const unsigned short* Xb = X + (size_t)b * K * NPIX;
    const int lr = lane >> 2;      // row-within-16 of this lane's 16B
    const int sp = lane & 3;       // physical 16B slot

    // one issue covers 16 rows (64 lanes x 16B = 1KB = 16 x 64B rows)
    auto stage = [&](int d, int k0) {
        const int kb = k0 >> 3;
#pragma unroll
        for (int i = 0; i < BN / 64; i++) {
            const int r0 = w * (BN / 4) + i * 16;
            const int r  = r0 + lr;
            const int sl = sp ^ (r & 3);
            GLOAD_LDS16(Xb + (((size_t)(kb + sl)) * NPIX + n0 + r) * 8,
                        Bsm + ((size_t)d * BN + r0) * 32);
        }
#pragma unroll
        for (int i = 0; i < BM / 64; i++) {
            const int r0 = w * (BM / 4) + i * 16;
            const int r  = r0 + lr;
            const int sl = sp ^ (r & 3);
            GLOAD_LDS16(W + (((size_t)(kb + sl)) * O + o0 + r) * 8,
                        Asm + ((size_t)d * BM + r0) * 32);
        }
    };

    stage(0, 0);
    __syncthreads();

    const int l16 = lane & 15;
    const int lq  = lane >> 4;

    int cur = 0;
    for (int k0 = 0; k0 < K; k0 += 32) {
        if (k0 + 32 < K) stage(cur ^ 1, k0 + 32);
        bf16x8 afr[MI], bfr[NJ];
#pragma unroll
        for (int i = 0; i < MI; i++) {
            const int r = wo + i * 16 + l16;
            afr[i] = *(const bf16x8*)&Asm[((size_t)cur * BM + r) * 32 +
                      (lq ^ (r & 3)) * 8];
        }
#pragma unroll
        for (int j = 0; j < NJ; j++) {
            const int r = wn + j * 16 + l16;
            bfr[j] = *(const bf16x8*)&Bsm[((size_t)cur * BN + r) * 32 +
                      (lq ^ (r & 3)) * 8];
        }
#pragma unroll
        for (int i = 0; i < MI; i++)
#pragma unroll
            for (int j = 0; j < NJ; j++)
                acc[i][j] = __builtin_amdgcn_mfma_f32_16x16x32_bf16(
                    afr[i], bfr[j], acc[i][j], 0, 0, 0);
        __syncthreads();
        cur ^= 1;
    }
    // after final barrier: As/Bs dead -> T may reuse smem.

    // epilogue. C/D: col = lane&15 (n), row = (lane>>4)*4 + reg (o)
    const int r0q = lq * 4;
    float scale[MI][4], shift[MI][4];
    if (EPI == 1) {
#pragma unroll
        for (int i = 0; i < MI; i++)
#pragma unroll
            for (int r = 0; r < 4; r++) {
                const int o = o0 + wo + i * 16 + r0q + r;
                const float inv = bng[o] / sqrtf(bnv[o] + 1e-5f);
                scale[i][r] = inv;
                shift[i][r] = bnb[o] - bnm[o] * inv;
            }
    } else if (EPI == 2) {
#pragma unroll
        for (int i = 0; i < MI; i++)
#pragma unroll
            for (int r = 0; r < 4; r++)
                shift[i][r] = bias[o0 + wo + i * 16 + r0q + r];
    }

#pragma unroll
    for (int i = 0; i < MI; i++) {
#pragma unroll
        for (int j = 0; j < NJ; j++) {
            const int nn = n0 + wn + j * 16 + l16;
            const int nl = wn + j * 16 + l16;           // n within tile
            const int ob = wo + i * 16 + r0q;           // o base within tile
            const size_t base = ((size_t)b * O + o0 + ob) * NPIX + nn;
            u16x4 p4;
#pragma unroll
            for (int r = 0; r < 4; r++) {
                const size_t off = base + (size_t)r * NPIX;
                float v = acc[i][j][r];
                if (EPI == 1) {
                    v = v * scale[i][r] + shift[i][r] + res[off];
                } else if (EPI == 2) {
                    v += shift[i][r];
                    v = v * fminf(fmaxf(v + 3.f, 0.f), 6.f) * (1.f / 6.f);
                }
                if (OMODE == 0 || OMODE == 3) {
                    if (ACC) v += Y[off];
                    Y[off] = v;
                }
                if (OMODE == 1) {
                    T[(size_t)(ob + r) * TSTR + nl] = f2bf(v);
                } else if (OMODE >= 2) {
                    p4[r] = f2bf(v);
                }
            }
            if (OMODE >= 2)
                *(u16x4*)(T + (size_t)nl * TSTR + ob) = p4;
        }
    }

    if (OMODE >= 1) {
        __syncthreads();
        constexpr int CNT = BM * BN / 2048;
        if (OMODE == 1) {
#pragma unroll
            for (int k = 0; k < CNT; k++) {
                const int idx = t + k * 256;
                const int o   = idx / (BN / 8);
                const int n8  = (idx % (BN / 8)) * 8;
                const u16x8 v = *(const u16x8*)(T + (size_t)o * TSTR + n8);
                *(u16x8*)(YB + ((size_t)b * O + o0 + o) * NPIX + n0 + n8) = v;
            }
        } else {
#pragma unroll
            for (int k = 0; k < CNT; k++) {
                const int idx = t + k * 256;
                const int oo  = idx / BN;
                const int nn  = idx % BN;
                const u16x8 v = *(const u16x8*)(T + (size_t)nn * TSTR + oo * 8);
                *(u16x8*)(YB + (((size_t)b * (O >> 3) + (o0 >> 3) + oo) * NPIX + n0 + nn) * 8) = v;
            }
        }
    }
}

// ---------------------------------------------------------------------------
// Depthwise 5x5 SAME, bf16 [c][n] in/out. fp32 LDS tile, 2 channels/block,
// register sliding window. Stride 44 padding.
// ---------------------------------------------------------------------------
__global__ __launch_bounds__(256)
void dwconv5x5_v3(const unsigned short* __restrict__ X, const float* __restrict__ Wd,
                  unsigned short* __restrict__ Y)
{
    __shared__ float tile[2 * 36 * 44];     // [ch][row 0..35][col 0..43], image+2 offset
    __shared__ float wl[64];                // [ch][25]
    const int t     = threadIdx.x;
    const int cpair = blockIdx.x % 384;
    const int b     = blockIdx.x / 384;
    const int cbase = cpair * 2;
    const unsigned short* xp = X + ((size_t)(b * 768 + cbase)) * NPIX;

    // zero whole tile (2*36*44 = 3168 floats = 792 float4)
#pragma unroll
    for (int k = 0; k < 4; k++) {
        const int i = t + k * 256;
        if (i < 792) {
            f32x4 z = {0.f, 0.f, 0.f, 0.f};
            *(f32x4*)(&tile[i * 4]) = z;
        }
    }
    if (t < 50) wl[(t / 25) * 32 + (t % 25)] = Wd[cbase * 25 + t];
    __syncthreads();

    const int ch = t >> 7;               // wave-uniform
    const int tm = t & 127;
    const int r  = tm >> 2;              // image row 0..31
    const int c8 = (tm & 3) * 8;         // image col base {0,8,16,24}

    // stage: 8 px -> fp32 interior [r+2][c8+2 .. +9]
    {
        const u16x8 v = *(const u16x8*)(xp + (size_t)ch * NPIX + r * 32 + c8);
        float* wp = &tile[ch * 1584 + (r + 2) * 44 + c8 + 2];
#pragma unroll
        for (int j = 0; j < 8; j += 2) {
            float2 f2v = make_float2(bf2f(v[j]), bf2f(v[j + 1]));
            *(float2*)(wp + j) = f2v;
        }
    }
    float wk[25];
#pragma unroll
    for (int i = 0; i < 25; i++) wk[i] = wl[ch * 32 + i];
    __syncthreads();

    float acc[8];
#pragma unroll
    for (int j = 0; j < 8; j++) acc[j] = 0.f;

#pragma unroll
    for (int ky = 0; ky < 5; ky++) {
        const float* rp = &tile[ch * 1584 + (r + ky) * 44 + c8];
        const f32x4 a = *(const f32x4*)(rp);
        const f32x4 bq = *(const f32x4*)(rp + 4);
        const f32x4 cq = *(const f32x4*)(rp + 8);
        const float in[12] = {a[0], a[1], a[2], a[3], bq[0], bq[1], bq[2], bq[3],
                              cq[0], cq[1], cq[2], cq[3]};
#pragma unroll
        for (int kx = 0; kx < 5; kx++) {
            const float wv = wk[ky * 5 + kx];
#pragma unroll
            for (int j = 0; j < 8; j++)
                acc[j] = fmaf(in[j + kx], wv, acc[j]);
        }
    }

    u16x8 o8;
#pragma unroll
    for (int j = 0; j < 8; j++) o8[j] = f2bf(acc[j]);
    *(u16x8*)(Y + ((size_t)(b * 768 + cbase + ch)) * NPIX + r * 32 + c8) = o8;
}

// ---------------------------------------------------------------------------
// Depthwise 3x3 + bias + hswish, blocked bf16 [coct][n][8] in -> blocked out.
// ---------------------------------------------------------------------------
__global__ __launch_bounds__(256)
void dwconv3x3_blk(const unsigned short* __restrict__ X, const float* __restrict__ Wd,
                   const float* __restrict__ bias, unsigned short* __restrict__ Y)
{
    __shared__ unsigned short tile[1024 * 8];
    __shared__ float wl[72];
    __shared__ float bb[8];
    const int t    = threadIdx.x;
    const int coct = blockIdx.x & 127;
    const int b    = blockIdx.x >> 7;
    const unsigned short* xp = X + ((size_t)(b * 128 + coct)) * NPIX * 8;
#pragma unroll
    for (int k = 0; k < 4; k++) {
        const int slot = t + k * 256;
        *(u16x8*)(&tile[slot * 8]) = *(const u16x8*)(xp + slot * 8);
    }
    if (t < 72) wl[t] = Wd[coct * 72 + t];
    if (t < 8)  bb[t] = bias[coct * 8 + t];
    __syncthreads();

    const int px0 = t * 4;
    const int h   = px0 >> 5;
    const int c0  = px0 & 31;

    float acc[8][4];
#pragma unroll
    for (int ch = 0; ch < 8; ch++)
#pragma unroll
        for (int j = 0; j < 4; j++) acc[ch][j] = bb[ch];

#pragma unroll
    for (int ky = 0; ky < 3; ky++) {
        const int rr = h + ky - 1;
        if (rr >= 0 && rr < 32) {
            u16x8 P[6];
#pragma unroll
            for (int m = 0; m < 6; m++) {
                const int col = c0 - 1 + m;
                const int colc = col < 0 ? 0 : (col > 31 ? 31 : col);
                u16x8 v = *(const u16x8*)(&tile[(rr * 32 + colc) * 8]);
                if (col < 0 || col > 31) v = zero8();
                P[m] = v;
            }
#pragma unroll
            for (int ch = 0; ch < 8; ch++) {
                float g[6];
#pragma unroll
                for (int m = 0; m < 6; m++) g[m] = bf2f(P[m][ch]);
#pragma unroll
                for (int j = 0; j < 4; j++)
#pragma unroll
                    for (int kx = 0; kx < 3; kx++)
                        acc[ch][j] = fmaf(g[j + kx], wl[ch * 9 + ky * 3 + kx], acc[ch][j]);
            }
        }
    }
    unsigned short* yp = Y + ((size_t)(b * 128 + coct)) * NPIX * 8 + (size_t)px0 * 8;
#pragma unroll
    for (int j = 0; j < 4; j++) {
        u16x8 o8;
#pragma unroll
        for (int ch = 0; ch < 8; ch++) {
            float v = acc[ch][j];
            v = v * fminf(fmaxf(v + 3.f, 0.f), 6.f) * (1.f / 6.f);
            o8[ch] = f2bf(v);
        }
        *(u16x8*)(yp + j * 8) = o8;
    }
}

// ---------------------------------------------------------------------------
// Grouped 32->32 1x1 (24 groups), in-place on bf16 [c][n] D.
// ---------------------------------------------------------------------------
__global__ __launch_bounds__(256)
void grouped_pw(unsigned short* __restrict__ D, const float* __restrict__ Wg)
{
    __shared__ float ws[1024];
    const int t     = threadIdx.x;
    const int blk   = blockIdx.x;          // (b*24+g)*4 + chunk
    const int chunk = blk & 3;
    const int bg    = blk >> 2;
    const int g     = bg % 24;
    const int b     = bg / 24;
    for (int i = t; i < 1024; i += 256) ws[i] = Wg[g * 1024 + i];
    __syncthreads();
    const int px = chunk * 256 + t;
    unsigned short* dp = D + ((size_t)(b * 768 + g * 32)) * NPIX + px;
    float in[32];
#pragma unroll
    for (int i = 0; i < 32; i++) in[i] = bf2f(dp[(size_t)i * NPIX]);
#pragma unroll
    for (int o = 0; o < 32; o++) {
        float s = 0.f;
#pragma unroll
        for (int i = 0; i < 32; i++) s = fmaf(ws[o * 32 + i], in[i], s);
        dp[(size_t)o * NPIX] = f2bf(s);
    }
}

// ---------------------------------------------------------------------------
// Attention kv via MFMA: one block per (b,h), 4 waves each over a 256-px
// n-chunk. Fragments loaded directly from global; final kv[33][32] to kvp.
// ---------------------------------------------------------------------------
__global__ __launch_bounds__(256)
void attn_kv_mfma(const unsigned short* __restrict__ qkv,
                  const unsigned short* __restrict__ dpw,
                  float* __restrict__ kvp)
{
    __shared__ float kvred[4][33 * 33];   // [wave][d*33+e], stride 33 pads banks
    const int t    = threadIdx.x;
    const int lane = t & 63;
    const int w    = t >> 6;
    const int bh   = blockIdx.x;
    const int b    = bh >> 4;
    const int h    = bh & 15;

    const unsigned short* base = (h < 8)
        ? qkv + ((size_t)(b * 768 + h * 96)) * NPIX
        : dpw + ((size_t)(b * 768 + (h - 8) * 96)) * NPIX;
    const unsigned short* kp = base + 32 * NPIX;
    const unsigned short* vp = base + 64 * NPIX;

    const int l16 = lane & 15;
    const int ko  = (lane >> 4) * 8;     // k-oct within the 32-wide step
    const int nb  = w * 256;

    f32x4 acc[3][2];
#pragma unroll
    for (int i = 0; i < 3; i++)
#pragma unroll
        for (int j = 0; j < 2; j++) {
            f32x4 z = {0.f, 0.f, 0.f, 0.f};
            acc[i][j] = z;
        }

    // constant ones-fragment: A-row 32 (d=32) is all-ones, rows 33..47 zero
    bf16x8 ones;
#pragma unroll
    for (int j = 0; j < 8; j++) ones[j] = (l16 == 0) ? (short)0x3F80 : (short)0;

#pragma unroll
    for (int s = 0; s < 8; s++) {
        const int n0 = nb + s * 32 + ko;
        const bf16x8 av0 = *(const bf16x8*)(vp + (size_t)l16 * NPIX + n0);
        const bf16x8 av1 = *(const bf16x8*)(vp + (size_t)(16 + l16) * NPIX + n0);
        const u16x8 k0 = *(const u16x8*)(kp + (size_t)l16 * NPIX + n0);
        const u16x8 k1 = *(const u16x8*)(kp + (size_t)(16 + l16) * NPIX + n0);
        bf16x8 bk0, bk1;
#pragma unroll
        for (int j = 0; j < 8; j++) {
            bk0[j] = (k0[j] & 0x8000u) ? (short)0 : (short)k0[j];   // relu (exact on bf16)
            bk1[j] = (k1[j] & 0x8000u) ? (short)0 : (short)k1[j];
        }
        acc[0][0] = __builtin_amdgcn_mfma_f32_16x16x32_bf16(av0,  bk0, acc[0][0], 0, 0, 0);
        acc[0][1] = __builtin_amdgcn_mfma_f32_16x16x32_bf16(av0,  bk1, acc[0][1], 0, 0, 0);
        acc[1][0] = __builtin_amdgcn_mfma_f32_16x16x32_bf16(av1,  bk0, acc[1][0], 0, 0, 0);
        acc[1][1] = __builtin_amdgcn_mfma_f32_16x16x32_bf16(av1,  bk1, acc[1][1], 0, 0, 0);
        acc[2][0] = __builtin_amdgcn_mfma_f32_16x16x32_bf16(ones, bk0, acc[2][0], 0, 0, 0);
        acc[2][1] = __builtin_amdgcn_mfma_f32_16x16x32_bf16(ones, bk1, acc[2][1], 0, 0, 0);
    }

    // write partials. C/D: row d = dt*16 + (lane>>4)*4 + r, col e = et*16 + l16
    const int rbase = (lane >> 4) * 4;
#pragma unroll
    for (int dt = 0; dt < 2; dt++)
#pragma unroll
        for (int et = 0; et < 2; et++)
#pragma unroll
            for (int r = 0; r < 4; r++)
                kvred[w][(dt * 16 + rbase + r) * 33 + et * 16 + l16] = acc[dt][et][r];
    if (rbase == 0) {               // d == 32 only (lanes 0..15, reg 0)
#pragma unroll
        for (int et = 0; et < 2; et++)
            kvred[w][32 * 33 + et * 16 + l16] = acc[2][et][0];
    }
    __syncthreads();

#pragma unroll
    for (int k = 0; k < 5; k++) {
        const int idx = t + k * 256;
        if (idx < 1056) {
            const int d = idx >> 5;
            const int e = idx & 31;
            const int a = d * 33 + e;
            kvp[(size_t)bh * 1056 + idx] =
                kvred[0][a] + kvred[1][a] + kvred[2][a] + kvred[3][a];
        }
    }
}

// ---------------------------------------------------------------------------
// Attention phase 2: load final kv, apply; OUT = blocked bf16
// att_t[b][64][1024][8]  (c = h*32 + db*8 + j)
// 1 pixel/thread (grid 1024 -> 16 waves/CU) + ds_read_b128 kv reads.
// ---------------------------------------------------------------------------
__global__ __launch_bounds__(256)
void attn_apply(const unsigned short* __restrict__ qkv,
                const unsigned short* __restrict__ dpw,
                const float* __restrict__ kvp, unsigned short* __restrict__ att)
{
    __shared__ float kvs[1056];
    const int t   = threadIdx.x;
    const int blk = blockIdx.x;           // bh*4 + qc
    const int qc  = blk & 3;
    const int bh  = blk >> 2;
    const int b   = bh >> 4;
    const int h   = bh & 15;
    for (int i = t; i < 264; i += 256)
        *(f32x4*)(&kvs[i * 4]) = *(const f32x4*)(kvp + (size_t)bh * 1056 + i * 4);
    __syncthreads();
    const unsigned short* qp = (h < 8)
        ? qkv + ((size_t)(b * 768 + h * 96)) * NPIX
        : dpw + ((size_t)(b * 768 + (h - 8) * 96)) * NPIX;
    const int n = qc * 256 + t;

    float q[32];
#pragma unroll
    for (int e = 0; e < 32; e++) q[e] = fmaxf(bf2f(qp[(size_t)e * NPIX + n]), 0.f);

    float den = 0.f;
#pragma unroll
    for (int eq = 0; eq < 8; eq++) {
        const f32x4 kvv = *(const f32x4*)(&kvs[1024 + eq * 4]);
#pragma unroll
        for (int j = 0; j < 4; j++)
            den = fmaf(kvv[j], q[eq * 4 + j], den);
    }
    const float inv = 1.f / (den + 1e-15f);

#pragma unroll
    for (int db = 0; db < 4; db++) {
        u16x8 o8;
#pragma unroll
        for (int jj = 0; jj < 8; jj++) {
            const int d = db * 8 + jj;
            float a = 0.f;
#pragma unroll
            for (int eq = 0; eq < 8; eq++) {
                const f32x4 kvv = *(const f32x4*)(&kvs[d * 32 + eq * 4]);
#pragma unroll
                for (int j = 0; j < 4; j++)
                    a = fmaf(kvv[j], q[eq * 4 + j], a);
            }
            o8[jj] = f2bf(a * inv);
        }
        *(u16x8*)(att + (((size_t)(b * 64 + h * 4 + db)) * NPIX + n) * 8) = o8;
    }
}

// ---------------------------------------------------------------------------
extern "C" void kernel_launch(void* const* d_in, const int* in_sizes, int n_in,
                              void* d_out, int out_size, void* d_ws, size_t ws_size,
                              hipStream_t stream)
{
    (void)in_sizes; (void)n_in; (void)out_size; (void)ws_size;

    const float* x      = (const float*)d_in[0];
    const float* y      = (const float*)d_in[1];
    const float* qkv_w  = (const float*)d_in[2];
    const float* dw5_w  = (const float*)d_in[3];
    const float* pwg_w  = (const float*)d_in[4];
    const float* proj_w = (const float*)d_in[5];
    const float* proj_g = (const float*)d_in[6];
    const float* proj_b = (const float*)d_in[7];
    const float* proj_m = (const float*)d_in[8];
    const float* proj_v = (const float*)d_in[9];
    const float* inv_w  = (const float*)d_in[10];
    const float* inv_b  = (const float*)d_in[11];
    const float* dwc_w  = (const float*)d_in[12];
    const float* dwc_b  = (const float*)d_in[13];
    const float* pw_w   = (const float*)d_in[14];
    const float* pw_g   = (const float*)d_in[15];
    const float* pw_b   = (const float*)d_in[16];
    const float* pw_m   = (const float*)d_in[17];
    const float* pw_v   = (const float*)d_in[18];

    float* ws = (float*)d_ws;
    unsigned short* wqkv_b  = (unsigned short*)(ws + WQKV_OFF);
    unsigned short* wproj_b = (unsigned short*)(ws + WPROJ_OFF);
    unsigned short* winv_b  = (unsigned short*)(ws + WINV_OFF);
    unsigned short* wpw_b   = (unsigned short*)(ws + WPW_OFF);
    unsigned short* wxt     = (unsigned short*)(ws + XT_OFF);
    unsigned short* wqkv    = (unsigned short*)(ws + QKV_OFF);
    unsigned short* wdpw    = (unsigned short*)(ws + DPW_OFF);
    unsigned short* watt    = (unsigned short*)(ws + ATT_OFF);
    float*          wkvp    = ws + KVP_OFF;
    float*          wt1     = ws + T1_OFF;
    unsigned short* wt1t    = (unsigned short*)(ws + T1T_OFF);
    unsigned short* wh1t    = (unsigned short*)(ws + H1T_OFF);
    unsigned short* wh2t    = (unsigned short*)(ws + H2T_OFF);
    float* out = (float*)d_out;

    // weights -> blocked bf16 (single launch)
    wconv_all<<<dim3(416), 256, 0, stream>>>(qkv_w, proj_w, inv_w, pw_w,
                                             wqkv_b, wproj_b, winv_b, wpw_b);

    for (int blk = 0; blk < 2; blk++) {
        const float* t = (blk == 0) ? x : y;

        // --- lite_mla ---
        xpose_f32_bf16<<<dim3(2048), 256, 0, stream>>>(t, wxt, 256);
        gemm_blk<128, 128, 0, false, 1><<<dim3(6, 128), 256, 0, stream>>>(
            wxt, wqkv_b, nullptr, wqkv, 768, 256,
            nullptr, nullptr, nullptr, nullptr, nullptr, nullptr);
        dwconv5x5_v3<<<dim3(6144), 256, 0, stream>>>(wqkv, dw5_w, wdpw);
        grouped_pw<<<dim3(1536), 256, 0, stream>>>(wdpw, pwg_w);
        attn_kv_mfma<<<dim3(256), 256, 0, stream>>>(wqkv, wdpw, wkvp);
        attn_apply<<<dim3(1024), 256, 0, stream>>>(wqkv, wdpw, wkvp, watt);
        gemm_blk<64, 64, 1, false, 3><<<dim3(4, 256), 256, 0, stream>>>(
            watt, wproj_b, wt1, wt1t, 256, 512,
            t, proj_g, proj_b, proj_m, proj_v, nullptr);

        // --- mbconv ---
        gemm_blk<128, 128, 2, false, 2><<<dim3(8, 128), 256, 0, stream>>>(
            wt1t, winv_b, nullptr, wh1t, 1024, 256,
            nullptr, nullptr, nullptr, nullptr, nullptr, inv_b);
        dwconv3x3_blk<<<dim3(2048), 256, 0, stream>>>(wh1t, dwc_w, dwc_b, wh2t);
        if (blk == 0) {
            gemm_blk<64, 64, 1, false, 0><<<dim3(4, 256), 256, 0, stream>>>(
                wh2t, wpw_b, out, nullptr, 256, 1024,
                wt1, pw_g, pw_b, pw_m, pw_v, nullptr);
        } else {
            gemm_blk<64, 64, 1, true, 0><<<dim3(4, 256), 256, 0, stream>>>(
                wh2t, wpw_b, out, nullptr, 256, 1024,
                wt1, pw_g, pw_b, pw_m, pw_v, nullptr);
        }
    }
}

// Round 13
// 328.959 us; speedup vs baseline: 1.1487x; 1.1487x over previous
//
#include <hip/hip_runtime.h>
#include <cstddef>

#define NPIX 1024   // H*W = 32*32

// ---------------------------------------------------------------------------
// Workspace layout (float-slot offsets). Peak 34,045,952 floats (136 MB).
// ---------------------------------------------------------------------------
static constexpr size_t WQKV_OFF  = 0;          //  98304 floats (768x256 bf16)
static constexpr size_t WPROJ_OFF = 98304;      //  65536 (256x512)
static constexpr size_t WINV_OFF  = 163840;     // 131072 (1024x256)
static constexpr size_t WPW_OFF   = 294912;     // 131072 (256x1024)
static constexpr size_t XT_OFF    = 425984;     // 2097152 (16x256x1024 bf16 blocked)
static constexpr size_t QKV_OFF   = 2523136;    // 6291456 (16x768x1024 bf16 [c][n])
static constexpr size_t DPW_OFF   = 8814592;    // 6291456
static constexpr size_t ATT_OFF   = 15106048;   // 4194304 (16x512x1024 bf16 blocked)
static constexpr size_t KVP_OFF   = 19300352;   // 270336 (256x1056 fp32, final kv)
static constexpr size_t T1_OFF    = 21463040;   // 4194304 (16x256x1024 fp32 [c][n])
static constexpr size_t T1T_OFF   = 25657344;   // 2097152 (16x32x1024x8 bf16 blocked)
static constexpr size_t H1T_OFF   = 425984;     // 8388608 (16x128x1024x8 bf16 blocked)
static constexpr size_t H2T_OFF   = 25657344;   // 8388608 (blocked; overwrites t1t after inv)

typedef __attribute__((ext_vector_type(8))) short bf16x8;
typedef __attribute__((ext_vector_type(8))) unsigned short u16x8;
typedef __attribute__((ext_vector_type(4))) unsigned short u16x4;
typedef __attribute__((ext_vector_type(4))) float f32x4;

__device__ inline unsigned short f2bf(float f) {
    union { float f; unsigned int u; } v; v.f = f;
    unsigned int u = v.u;
    u += 0x7FFFu + ((u >> 16) & 1u);        // round-to-nearest-even
    return (unsigned short)(u >> 16);
}
__device__ inline float bf2f(unsigned short u) {
    union { float f; unsigned int u; } v; v.u = ((unsigned int)u) << 16;
    return v.f;
}
__device__ inline u16x8 zero8() {
    u16x8 z = {0, 0, 0, 0, 0, 0, 0, 0};
    return z;
}

// ---------------------------------------------------------------------------
// Weight convert (all 4 weights in ONE launch): fp32 [O][K] -> bf16 [K/8][O][8]
// ---------------------------------------------------------------------------
__global__ __launch_bounds__(256)
void wconv_all(const float* __restrict__ w0, const float* __restrict__ w1,
               const float* __restrict__ w2, const float* __restrict__ w3,
               unsigned short* __restrict__ d0, unsigned short* __restrict__ d1,
               unsigned short* __restrict__ d2, unsigned short* __restrict__ d3)
{
    const int bid = blockIdx.x;
    const float* W; unsigned short* WB; int O, K, base;
    if (bid < 96)       { W = w0; WB = d0; O = 768;  K = 256;  base = 0;   }
    else if (bid < 160) { W = w1; WB = d1; O = 256;  K = 512;  base = 96;  }
    else if (bid < 288) { W = w2; WB = d2; O = 1024; K = 256;  base = 160; }
    else                { W = w3; WB = d3; O = 256;  K = 1024; base = 288; }
    const int idx = (bid - base) * 256 + threadIdx.x;
    if (idx >= O * (K >> 3)) return;
    const int o = idx % O;
    const int koct = idx / O;
    u16x8 v;
#pragma unroll
    for (int j = 0; j < 8; j++) v[j] = f2bf(W[(size_t)o * K + koct * 8 + j]);
    *(u16x8*)(WB + ((size_t)koct * O + o) * 8) = v;
}

// ---------------------------------------------------------------------------
// Transpose: fp32 [b][C][1024] -> blocked bf16 [b][C/8][1024][8]
// ---------------------------------------------------------------------------
__global__ __launch_bounds__(256)
void xpose_f32_bf16(const float* __restrict__ X, unsigned short* __restrict__ XT,
                    const int C)
{
    __shared__ float tt[8][260];
    const int t = threadIdx.x;
    const int octs = C >> 3;
    const int strips = octs * 4;
    const int b = blockIdx.x / strips;
    const int rem = blockIdx.x - b * strips;
    const int coct = rem >> 2;
    const int n0 = (rem & 3) * 256;

    const int cc = t >> 5;
    const int c8 = (t & 31) * 8;
    const float* xp = X + ((size_t)b * C + coct * 8 + cc) * NPIX + n0 + c8;
    *(float4*)(&tt[cc][c8])     = *(const float4*)(xp);
    *(float4*)(&tt[cc][c8 + 4]) = *(const float4*)(xp + 4);
    __syncthreads();
    u16x8 v;
#pragma unroll
    for (int j = 0; j < 8; j++) v[j] = f2bf(tt[j][t]);
    *(u16x8*)(XT + (((size_t)b * octs + coct) * NPIX + n0 + t) * 8) = v;
}

// ---------------------------------------------------------------------------
// MFMA GEMM, DIRECT global->VGPR fragments (no LDS staging, NO main-loop
// barriers). Both operands blocked bf16 [K/8][rows][8]: a 16-lane quarter
// reads 256B contiguous -> fully coalesced frag loads; W panels are
// L2-resident, X re-reads served by L2/L3.
//   X: [b][K/8][1024][8], W: [K/8][O][8];  Y = W·X (+ epilogue)
// Block tile BM x BN, 4 waves; BN=128: 2x2 waves; BN=64: 4x1 waves.
// Explicit 2-deep register double-buffer (named sets, static indexing).
// EPI: 0 plain, 1 BN+residual(+ACC), 2 bias+hswish.
// OMODE: 0 fp32 [c][n]; 1 bf16 [c][n] (LDS-transposed); 2 blocked bf16;
//        3 fp32 [c][n] + blocked bf16 (dual)
// ---------------------------------------------------------------------------
template<int BM, int BN, int EPI, bool ACC, int OMODE>
__global__ __launch_bounds__(256)
void gemm_direct(const unsigned short* __restrict__ X, const unsigned short* __restrict__ W,
                 float* __restrict__ Y, unsigned short* __restrict__ YB,
                 const int O, const int K,
                 const float* __restrict__ res,
                 const float* __restrict__ bng, const float* __restrict__ bnb,
                 const float* __restrict__ bnm, const float* __restrict__ bnv,
                 const float* __restrict__ bias)
{
    constexpr int TN = NPIX / BN;               // n-tiles per image
    constexpr int WAVES_N = (BN >= 128) ? 2 : 1;
    constexpr int WM = BM / (4 / WAVES_N);
    constexpr int MI = WM / 16;
    constexpr int NJ = 4;                       // wave n-extent always 64
    constexpr int TSTR = (OMODE == 1) ? (BN + 8) : (BM + 8);
    constexpr int TSZ  = (OMODE == 1) ? BM * TSTR : ((OMODE >= 2) ? BN * TSTR : 64);
    __shared__ unsigned short T[TSZ];           // epilogue transpose only

    const int t    = threadIdx.x;
    const int lane = t & 63;
    const int w    = t >> 6;

    // XCD-bijective block swizzle (all grids are multiples of 8)
    const int gx  = gridDim.x;
    const int nwg = gx * gridDim.y;
    int bid = blockIdx.y * gx + blockIdx.x;
    bid = (bid & 7) * (nwg >> 3) + (bid >> 3);
    const int bx = bid % gx;
    const int by = bid / gx;

    const int o0 = bx * BM;
    const int b  = by / TN;
    const int n0 = (by % TN) * BN;

    const int wn = (WAVES_N == 2) ? (w & 1) * 64 : 0;
    const int wo = (WAVES_N == 2) ? (w >> 1) * WM : w * WM;

    const int l16 = lane & 15;
    const int lq  = lane >> 4;

    f32x4 acc[MI][NJ];
#pragma unroll
    for (int i = 0; i < MI; i++)
#pragma unroll
        for (int j = 0; j < NJ; j++) {
            f32x4 z = {0.f, 0.f, 0.f, 0.f};
            acc[i][j] = z;
        }

    // fragment base pointers (quarter-wave lq owns k-oct kb+lq)
    // A layout: (koct*O + o)*8 ;  B layout: b-image stride K*NPIX u16,
    // within image (koct*NPIX + n)*8.
    const unsigned short* Ab = W + ((size_t)lq * O + o0 + wo + l16) * 8;
    const unsigned short* Bb = X + (size_t)b * K * NPIX
                                 + ((size_t)lq * NPIX + n0 + wn + l16) * 8;
    const size_t strideA = (size_t)O * 8;       // per k-oct
    const size_t strideB = (size_t)NPIX * 8;

    bf16x8 aA[MI], bA[NJ], aB[MI], bB[NJ];

    auto ldA = [&](bf16x8* fr, int kb) {
#pragma unroll
        for (int i = 0; i < MI; i++)
            fr[i] = *(const bf16x8*)(Ab + (size_t)kb * strideA + i * 128);
    };
    auto ldB = [&](bf16x8* fr, int kb) {
#pragma unroll
        for (int j = 0; j < NJ; j++)
            fr[j] = *(const bf16x8*)(Bb + (size_t)kb * strideB + j * 128);
    };
    auto domfma = [&](bf16x8* af, bf16x8* bf) {
#pragma unroll
        for (int i = 0; i < MI; i++)
#pragma unroll
            for (int j = 0; j < NJ; j++)
                acc[i][j] = __builtin_amdgcn_mfma_f32_16x16x32_bf16(
                    af[i], bf[j], acc[i][j], 0, 0, 0);
    };

    const int octs = K >> 3;                    // multiple of 8 (K % 64 == 0)
    ldA(aA, 0); ldB(bA, 0);
    for (int kb = 0; kb < octs; kb += 8) {
        ldA(aB, kb + 4); ldB(bB, kb + 4);       // always in range (octs % 8 == 0)
        domfma(aA, bA);
        if (kb + 8 < octs) { ldA(aA, kb + 8); ldB(bA, kb + 8); }
        domfma(aB, bB);
    }

    // epilogue. C/D: col = lane&15 (n), row = (lane>>4)*4 + reg (o)
    const int r0q = lq * 4;
    float scale[MI][4], shift[MI][4];
    if (EPI == 1) {
#pragma unroll
        for (int i = 0; i < MI; i++)
#pragma unroll
            for (int r = 0; r < 4; r++) {
                const int o = o0 + wo + i * 16 + r0q + r;
                const float inv = bng[o] / sqrtf(bnv[o] + 1e-5f);
                scale[i][r] = inv;
                shift[i][r] = bnb[o] - bnm[o] * inv;
            }
    } else if (EPI == 2) {
#pragma unroll
        for (int i = 0; i < MI; i++)
#pragma unroll
            for (int r = 0; r < 4; r++)
                shift[i][r] = bias[o0 + wo + i * 16 + r0q + r];
    }

#pragma unroll
    for (int i = 0; i < MI; i++) {
#pragma unroll
        for (int j = 0; j < NJ; j++) {
            const int nn = n0 + wn + j * 16 + l16;
            const int nl = wn + j * 16 + l16;           // n within tile
            const int ob = wo + i * 16 + r0q;           // o base within tile
            const size_t base = ((size_t)b * O + o0 + ob) * NPIX + nn;
            u16x4 p4;
#pragma unroll
            for (int r = 0; r < 4; r++) {
                const size_t off = base + (size_t)r * NPIX;
                float v = acc[i][j][r];
                if (EPI == 1) {
                    v = v * scale[i][r] + shift[i][r] + res[off];
                } else if (EPI == 2) {
                    v += shift[i][r];
                    v = v * fminf(fmaxf(v + 3.f, 0.f), 6.f) * (1.f / 6.f);
                }
                if (OMODE == 0 || OMODE == 3) {
                    if (ACC) v += Y[off];
                    Y[off] = v;
                }
                if (OMODE == 1) {
                    T[(size_t)(ob + r) * TSTR + nl] = f2bf(v);
                } else if (OMODE >= 2) {
                    p4[r] = f2bf(v);
                }
            }
            if (OMODE >= 2)
                *(u16x4*)(T + (size_t)nl * TSTR + ob) = p4;
        }
    }

    if (OMODE >= 1) {
        __syncthreads();
        constexpr int CNT = BM * BN / 2048;
        if (OMODE == 1) {
#pragma unroll
            for (int k = 0; k < CNT; k++) {
                const int idx = t + k * 256;
                const int o   = idx / (BN / 8);
                const int n8  = (idx % (BN / 8)) * 8;
                const u16x8 v = *(const u16x8*)(T + (size_t)o * TSTR + n8);
                *(u16x8*)(YB + ((size_t)b * O + o0 + o) * NPIX + n0 + n8) = v;
            }
        } else {
#pragma unroll
            for (int k = 0; k < CNT; k++) {
                const int idx = t + k * 256;
                const int oo  = idx / BN;
                const int nn  = idx % BN;
                const u16x8 v = *(const u16x8*)(T + (size_t)nn * TSTR + oo * 8);
                *(u16x8*)(YB + (((size_t)b * (O >> 3) + (o0 >> 3) + oo) * NPIX + n0 + nn) * 8) = v;
            }
        }
    }
}

// ---------------------------------------------------------------------------
// Depthwise 5x5 SAME, bf16 [c][n] in/out. fp32 LDS tile, 2 channels/block,
// register sliding window. Stride 44 padding.
// ---------------------------------------------------------------------------
__global__ __launch_bounds__(256)
void dwconv5x5_v3(const unsigned short* __restrict__ X, const float* __restrict__ Wd,
                  unsigned short* __restrict__ Y)
{
    __shared__ float tile[2 * 36 * 44];     // [ch][row 0..35][col 0..43], image+2 offset
    __shared__ float wl[64];                // [ch][25]
    const int t     = threadIdx.x;
    const int cpair = blockIdx.x % 384;
    const int b     = blockIdx.x / 384;
    const int cbase = cpair * 2;
    const unsigned short* xp = X + ((size_t)(b * 768 + cbase)) * NPIX;

    // zero whole tile (2*36*44 = 3168 floats = 792 float4)
#pragma unroll
    for (int k = 0; k < 4; k++) {
        const int i = t + k * 256;
        if (i < 792) {
            f32x4 z = {0.f, 0.f, 0.f, 0.f};
            *(f32x4*)(&tile[i * 4]) = z;
        }
    }
    if (t < 50) wl[(t / 25) * 32 + (t % 25)] = Wd[cbase * 25 + t];
    __syncthreads();

    const int ch = t >> 7;               // wave-uniform
    const int tm = t & 127;
    const int r  = tm >> 2;              // image row 0..31
    const int c8 = (tm & 3) * 8;         // image col base {0,8,16,24}

    // stage: 8 px -> fp32 interior [r+2][c8+2 .. +9]
    {
        const u16x8 v = *(const u16x8*)(xp + (size_t)ch * NPIX + r * 32 + c8);
        float* wp = &tile[ch * 1584 + (r + 2) * 44 + c8 + 2];
#pragma unroll
        for (int j = 0; j < 8; j += 2) {
            float2 f2v = make_float2(bf2f(v[j]), bf2f(v[j + 1]));
            *(float2*)(wp + j) = f2v;
        }
    }
    float wk[25];
#pragma unroll
    for (int i = 0; i < 25; i++) wk[i] = wl[ch * 32 + i];
    __syncthreads();

    float acc[8];
#pragma unroll
    for (int j = 0; j < 8; j++) acc[j] = 0.f;

#pragma unroll
    for (int ky = 0; ky < 5; ky++) {
        const float* rp = &tile[ch * 1584 + (r + ky) * 44 + c8];
        const f32x4 a = *(const f32x4*)(rp);
        const f32x4 bq = *(const f32x4*)(rp + 4);
        const f32x4 cq = *(const f32x4*)(rp + 8);
        const float in[12] = {a[0], a[1], a[2], a[3], bq[0], bq[1], bq[2], bq[3],
                              cq[0], cq[1], cq[2], cq[3]};
#pragma unroll
        for (int kx = 0; kx < 5; kx++) {
            const float wv = wk[ky * 5 + kx];
#pragma unroll
            for (int j = 0; j < 8; j++)
                acc[j] = fmaf(in[j + kx], wv, acc[j]);
        }
    }

    u16x8 o8;
#pragma unroll
    for (int j = 0; j < 8; j++) o8[j] = f2bf(acc[j]);
    *(u16x8*)(Y + ((size_t)(b * 768 + cbase + ch)) * NPIX + r * 32 + c8) = o8;
}

// ---------------------------------------------------------------------------
// Depthwise 3x3 + bias + hswish, blocked bf16 [coct][n][8] in -> blocked out.
// ---------------------------------------------------------------------------
__global__ __launch_bounds__(256)
void dwconv3x3_blk(const unsigned short* __restrict__ X, const float* __restrict__ Wd,
                   const float* __restrict__ bias, unsigned short* __restrict__ Y)
{
    __shared__ unsigned short tile[1024 * 8];
    __shared__ float wl[72];
    __shared__ float bb[8];
    const int t    = threadIdx.x;
    const int coct = blockIdx.x & 127;
    const int b    = blockIdx.x >> 7;
    const unsigned short* xp = X + ((size_t)(b * 128 + coct)) * NPIX * 8;
#pragma unroll
    for (int k = 0; k < 4; k++) {
        const int slot = t + k * 256;
        *(u16x8*)(&tile[slot * 8]) = *(const u16x8*)(xp + slot * 8);
    }
    if (t < 72) wl[t] = Wd[coct * 72 + t];
    if (t < 8)  bb[t] = bias[coct * 8 + t];
    __syncthreads();

    const int px0 = t * 4;
    const int h   = px0 >> 5;
    const int c0  = px0 & 31;

    float acc[8][4];
#pragma unroll
    for (int ch = 0; ch < 8; ch++)
#pragma unroll
        for (int j = 0; j < 4; j++) acc[ch][j] = bb[ch];

#pragma unroll
    for (int ky = 0; ky < 3; ky++) {
        const int rr = h + ky - 1;
        if (rr >= 0 && rr < 32) {
            u16x8 P[6];
#pragma unroll
            for (int m = 0; m < 6; m++) {
                const int col = c0 - 1 + m;
                const int colc = col < 0 ? 0 : (col > 31 ? 31 : col);
                u16x8 v = *(const u16x8*)(&tile[(rr * 32 + colc) * 8]);
                if (col < 0 || col > 31) v = zero8();
                P[m] = v;
            }
#pragma unroll
            for (int ch = 0; ch < 8; ch++) {
                float g[6];
#pragma unroll
                for (int m = 0; m < 6; m++) g[m] = bf2f(P[m][ch]);
#pragma unroll
                for (int j = 0; j < 4; j++)
#pragma unroll
                    for (int kx = 0; kx < 3; kx++)
                        acc[ch][j] = fmaf(g[j + kx], wl[ch * 9 + ky * 3 + kx], acc[ch][j]);
            }
        }
    }
    unsigned short* yp = Y + ((size_t)(b * 128 + coct)) * NPIX * 8 + (size_t)px0 * 8;
#pragma unroll
    for (int j = 0; j < 4; j++) {
        u16x8 o8;
#pragma unroll
        for (int ch = 0; ch < 8; ch++) {
            float v = acc[ch][j];
            v = v * fminf(fmaxf(v + 3.f, 0.f), 6.f) * (1.f / 6.f);
            o8[ch] = f2bf(v);
        }
        *(u16x8*)(yp + j * 8) = o8;
    }
}

// ---------------------------------------------------------------------------
// Grouped 32->32 1x1 (24 groups), in-place on bf16 [c][n] D.
// ---------------------------------------------------------------------------
__global__ __launch_bounds__(256)
void grouped_pw(unsigned short* __restrict__ D, const float* __restrict__ Wg)
{
    __shared__ float ws[1024];
    const int t     = threadIdx.x;
    const int blk   = blockIdx.x;          // (b*24+g)*4 + chunk
    const int chunk = blk & 3;
    const int bg    = blk >> 2;
    const int g     = bg % 24;
    const int b     = bg / 24;
    for (int i = t; i < 1024; i += 256) ws[i] = Wg[g * 1024 + i];
    __syncthreads();
    const int px = chunk * 256 + t;
    unsigned short* dp = D + ((size_t)(b * 768 + g * 32)) * NPIX + px;
    float in[32];
#pragma unroll
    for (int i = 0; i < 32; i++) in[i] = bf2f(dp[(size_t)i * NPIX]);
#pragma unroll
    for (int o = 0; o < 32; o++) {
        float s = 0.f;
#pragma unroll
        for (int i = 0; i < 32; i++) s = fmaf(ws[o * 32 + i], in[i], s);
        dp[(size_t)o * NPIX] = f2bf(s);
    }
}

// ---------------------------------------------------------------------------
// Attention kv via MFMA: one block per (b,h), 4 waves each over a 256-px
// n-chunk. Fragments loaded directly from global; final kv[33][32] to kvp.
// ---------------------------------------------------------------------------
__global__ __launch_bounds__(256)
void attn_kv_mfma(const unsigned short* __restrict__ qkv,
                  const unsigned short* __restrict__ dpw,
                  float* __restrict__ kvp)
{
    __shared__ float kvred[4][33 * 33];   // [wave][d*33+e], stride 33 pads banks
    const int t    = threadIdx.x;
    const int lane = t & 63;
    const int w    = t >> 6;
    const int bh   = blockIdx.x;
    const int b    = bh >> 4;
    const int h    = bh & 15;

    const unsigned short* base = (h < 8)
        ? qkv + ((size_t)(b * 768 + h * 96)) * NPIX
        : dpw + ((size_t)(b * 768 + (h - 8) * 96)) * NPIX;
    const unsigned short* kp = base + 32 * NPIX;
    const unsigned short* vp = base + 64 * NPIX;

    const int l16 = lane & 15;
    const int ko  = (lane >> 4) * 8;     // k-oct within the 32-wide step
    const int nb  = w * 256;

    f32x4 acc[3][2];
#pragma unroll
    for (int i = 0; i < 3; i++)
#pragma unroll
        for (int j = 0; j < 2; j++) {
            f32x4 z = {0.f, 0.f, 0.f, 0.f};
            acc[i][j] = z;
        }

    // constant ones-fragment: A-row 32 (d=32) is all-ones, rows 33..47 zero
    bf16x8 ones;
#pragma unroll
    for (int j = 0; j < 8; j++) ones[j] = (l16 == 0) ? (short)0x3F80 : (short)0;

#pragma unroll
    for (int s = 0; s < 8; s++) {
        const int n0 = nb + s * 32 + ko;
        const bf16x8 av0 = *(const bf16x8*)(vp + (size_t)l16 * NPIX + n0);
        const bf16x8 av1 = *(const bf16x8*)(vp + (size_t)(16 + l16) * NPIX + n0);
        const u16x8 k0 = *(const u16x8*)(kp + (size_t)l16 * NPIX + n0);
        const u16x8 k1 = *(const u16x8*)(kp + (size_t)(16 + l16) * NPIX + n0);
        bf16x8 bk0, bk1;
#pragma unroll
        for (int j = 0; j < 8; j++) {
            bk0[j] = (k0[j] & 0x8000u) ? (short)0 : (short)k0[j];   // relu (exact on bf16)
            bk1[j] = (k1[j] & 0x8000u) ? (short)0 : (short)k1[j];
        }
        acc[0][0] = __builtin_amdgcn_mfma_f32_16x16x32_bf16(av0,  bk0, acc[0][0], 0, 0, 0);
        acc[0][1] = __builtin_amdgcn_mfma_f32_16x16x32_bf16(av0,  bk1, acc[0][1], 0, 0, 0);
        acc[1][0] = __builtin_amdgcn_mfma_f32_16x16x32_bf16(av1,  bk0, acc[1][0], 0, 0, 0);
        acc[1][1] = __builtin_amdgcn_mfma_f32_16x16x32_bf16(av1,  bk1, acc[1][1], 0, 0, 0);
        acc[2][0] = __builtin_amdgcn_mfma_f32_16x16x32_bf16(ones, bk0, acc[2][0], 0, 0, 0);
        acc[2][1] = __builtin_amdgcn_mfma_f32_16x16x32_bf16(ones, bk1, acc[2][1], 0, 0, 0);
    }

    // write partials. C/D: row d = dt*16 + (lane>>4)*4 + r, col e = et*16 + l16
    const int rbase = (lane >> 4) * 4;
#pragma unroll
    for (int dt = 0; dt < 2; dt++)
#pragma unroll
        for (int et = 0; et < 2; et++)
#pragma unroll
            for (int r = 0; r < 4; r++)
                kvred[w][(dt * 16 + rbase + r) * 33 + et * 16 + l16] = acc[dt][et][r];
    if (rbase == 0) {               // d == 32 only (lanes 0..15, reg 0)
#pragma unroll
        for (int et = 0; et < 2; et++)
            kvred[w][32 * 33 + et * 16 + l16] = acc[2][et][0];
    }
    __syncthreads();

#pragma unroll
    for (int k = 0; k < 5; k++) {
        const int idx = t + k * 256;
        if (idx < 1056) {
            const int d = idx >> 5;
            const int e = idx & 31;
            const int a = d * 33 + e;
            kvp[(size_t)bh * 1056 + idx] =
                kvred[0][a] + kvred[1][a] + kvred[2][a] + kvred[3][a];
        }
    }
}

// ---------------------------------------------------------------------------
// Attention phase 2: load final kv, apply; OUT = blocked bf16
// att_t[b][64][1024][8]  (c = h*32 + db*8 + j)
// 1 pixel/thread (grid 1024 -> 16 waves/CU) + ds_read_b128 kv reads.
// ---------------------------------------------------------------------------
__global__ __launch_bounds__(256)
void attn_apply(const unsigned short* __restrict__ qkv,
                const unsigned short* __restrict__ dpw,
                const float* __restrict__ kvp, unsigned short* __restrict__ att)
{
    __shared__ float kvs[1056];
    const int t   = threadIdx.x;
    const int blk = blockIdx.x;           // bh*4 + qc
    const int qc  = blk & 3;
    const int bh  = blk >> 2;
    const int b   = bh >> 4;
    const int h   = bh & 15;
    for (int i = t; i < 264; i += 256)
        *(f32x4*)(&kvs[i * 4]) = *(const f32x4*)(kvp + (size_t)bh * 1056 + i * 4);
    __syncthreads();
    const unsigned short* qp = (h < 8)
        ? qkv + ((size_t)(b * 768 + h * 96)) * NPIX
        : dpw + ((size_t)(b * 768 + (h - 8) * 96)) * NPIX;
    const int n = qc * 256 + t;

    float q[32];
#pragma unroll
    for (int e = 0; e < 32; e++) q[e] = fmaxf(bf2f(qp[(size_t)e * NPIX + n]), 0.f);

    float den = 0.f;
#pragma unroll
    for (int eq = 0; eq < 8; eq++) {
        const f32x4 kvv = *(const f32x4*)(&kvs[1024 + eq * 4]);
#pragma unroll
        for (int j = 0; j < 4; j++)
            den = fmaf(kvv[j], q[eq * 4 + j], den);
    }
    const float inv = 1.f / (den + 1e-15f);

#pragma unroll
    for (int db = 0; db < 4; db++) {
        u16x8 o8;
#pragma unroll
        for (int jj = 0; jj < 8; jj++) {
            const int d = db * 8 + jj;
            float a = 0.f;
#pragma unroll
            for (int eq = 0; eq < 8; eq++) {
                const f32x4 kvv = *(const f32x4*)(&kvs[d * 32 + eq * 4]);
#pragma unroll
                for (int j = 0; j < 4; j++)
                    a = fmaf(kvv[j], q[eq * 4 + j], a);
            }
            o8[jj] = f2bf(a * inv);
        }
        *(u16x8*)(att + (((size_t)(b * 64 + h * 4 + db)) * NPIX + n) * 8) = o8;
    }
}

// ---------------------------------------------------------------------------
extern "C" void kernel_launch(void* const* d_in, const int* in_sizes, int n_in,
                              void* d_out, int out_size, void* d_ws, size_t ws_size,
                              hipStream_t stream)
{
    (void)in_sizes; (void)n_in; (void)out_size; (void)ws_size;

    const float* x      = (const float*)d_in[0];
    const float* y      = (const float*)d_in[1];
    const float* qkv_w  = (const float*)d_in[2];
    const float* dw5_w  = (const float*)d_in[3];
    const float* pwg_w  = (const float*)d_in[4];
    const float* proj_w = (const float*)d_in[5];
    const float* proj_g = (const float*)d_in[6];
    const float* proj_b = (const float*)d_in[7];
    const float* proj_m = (const float*)d_in[8];
    const float* proj_v = (const float*)d_in[9];
    const float* inv_w  = (const float*)d_in[10];
    const float* inv_b  = (const float*)d_in[11];
    const float* dwc_w  = (const float*)d_in[12];
    const float* dwc_b  = (const float*)d_in[13];
    const float* pw_w   = (const float*)d_in[14];
    const float* pw_g   = (const float*)d_in[15];
    const float* pw_b   = (const float*)d_in[16];
    const float* pw_m   = (const float*)d_in[17];
    const float* pw_v   = (const float*)d_in[18];

    float* ws = (float*)d_ws;
    unsigned short* wqkv_b  = (unsigned short*)(ws + WQKV_OFF);
    unsigned short* wproj_b = (unsigned short*)(ws + WPROJ_OFF);
    unsigned short* winv_b  = (unsigned short*)(ws + WINV_OFF);
    unsigned short* wpw_b   = (unsigned short*)(ws + WPW_OFF);
    unsigned short* wxt     = (unsigned short*)(ws + XT_OFF);
    unsigned short* wqkv    = (unsigned short*)(ws + QKV_OFF);
    unsigned short* wdpw    = (unsigned short*)(ws + DPW_OFF);
    unsigned short* watt    = (unsigned short*)(ws + ATT_OFF);
    float*          wkvp    = ws + KVP_OFF;
    float*          wt1     = ws + T1_OFF;
    unsigned short* wt1t    = (unsigned short*)(ws + T1T_OFF);
    unsigned short* wh1t    = (unsigned short*)(ws + H1T_OFF);
    unsigned short* wh2t    = (unsigned short*)(ws + H2T_OFF);
    float* out = (float*)d_out;

    // weights -> blocked bf16 (single launch)
    wconv_all<<<dim3(416), 256, 0, stream>>>(qkv_w, proj_w, inv_w, pw_w,
                                             wqkv_b, wproj_b, winv_b, wpw_b);

    for (int blk = 0; blk < 2; blk++) {
        const float* t = (blk == 0) ? x : y;

        // --- lite_mla ---
        xpose_f32_bf16<<<dim3(2048), 256, 0, stream>>>(t, wxt, 256);
        gemm_direct<128, 128, 0, false, 1><<<dim3(6, 128), 256, 0, stream>>>(
            wxt, wqkv_b, nullptr, wqkv, 768, 256,
            nullptr, nullptr, nullptr, nullptr, nullptr, nullptr);
        dwconv5x5_v3<<<dim3(6144), 256, 0, stream>>>(wqkv, dw5_w, wdpw);
        grouped_pw<<<dim3(1536), 256, 0, stream>>>(wdpw, pwg_w);
        attn_kv_mfma<<<dim3(256), 256, 0, stream>>>(wqkv, wdpw, wkvp);
        attn_apply<<<dim3(1024), 256, 0, stream>>>(wqkv, wdpw, wkvp, watt);
        gemm_direct<64, 64, 1, false, 3><<<dim3(4, 256), 256, 0, stream>>>(
            watt, wproj_b, wt1, wt1t, 256, 512,
            t, proj_g, proj_b, proj_m, proj_v, nullptr);

        // --- mbconv ---
        gemm_direct<128, 128, 2, false, 2><<<dim3(8, 128), 256, 0, stream>>>(
            wt1t, winv_b, nullptr, wh1t, 1024, 256,
            nullptr, nullptr, nullptr, nullptr, nullptr, inv_b);
        dwconv3x3_blk<<<dim3(2048), 256, 0, stream>>>(wh1t, dwc_w, dwc_b, wh2t);
        if (blk == 0) {
            gemm_direct<64, 64, 1, false, 0><<<dim3(4, 256), 256, 0, stream>>>(
                wh2t, wpw_b, out, nullptr, 256, 1024,
                wt1, pw_g, pw_b, pw_m, pw_v, nullptr);
        } else {
            gemm_direct<64, 64, 1, true, 0><<<dim3(4, 256), 256, 0, stream>>>(
                wh2t, wpw_b, out, nullptr, 256, 1024,
                wt1, pw_g, pw_b, pw_m, pw_v, nullptr);
        }
    }
}

// Round 14
// 312.203 us; speedup vs baseline: 1.2104x; 1.0537x over previous
//
#include <hip/hip_runtime.h>
#include <cstddef>

#define NPIX 1024   // H*W = 32*32

// ---------------------------------------------------------------------------
// Workspace layout (float-slot offsets). Peak 34,045,952 floats (136 MB).
// ---------------------------------------------------------------------------
static constexpr size_t WQKV_OFF  = 0;          //  98304 floats (768x256 bf16)
static constexpr size_t WPROJ_OFF = 98304;      //  65536 (256x512)
static constexpr size_t WINV_OFF  = 163840;     // 131072 (1024x256)
static constexpr size_t WPW_OFF   = 294912;     // 131072 (256x1024)
static constexpr size_t XT_OFF    = 425984;     // 2097152 (16x256x1024 bf16 blocked)
static constexpr size_t QKV_OFF   = 2523136;    // 6291456 (16x768x1024 bf16 [c][n])
static constexpr size_t DPW_OFF   = 8814592;    // 6291456
static constexpr size_t ATT_OFF   = 15106048;   // 4194304 (16x512x1024 bf16 blocked)
static constexpr size_t T1_OFF    = 21463040;   // 4194304 (16x256x1024 fp32 [c][n])
static constexpr size_t T1T_OFF   = 25657344;   // 2097152 (16x32x1024x8 bf16 blocked)
static constexpr size_t H1T_OFF   = 425984;     // 8388608 (16x128x1024x8 bf16 blocked)
static constexpr size_t H2T_OFF   = 25657344;   // 8388608 (blocked; overwrites t1t after inv)

typedef __attribute__((ext_vector_type(8))) short bf16x8;
typedef __attribute__((ext_vector_type(8))) unsigned short u16x8;
typedef __attribute__((ext_vector_type(4))) unsigned short u16x4;
typedef __attribute__((ext_vector_type(4))) float f32x4;

__device__ inline unsigned short f2bf(float f) {
    union { float f; unsigned int u; } v; v.f = f;
    unsigned int u = v.u;
    u += 0x7FFFu + ((u >> 16) & 1u);        // round-to-nearest-even
    return (unsigned short)(u >> 16);
}
__device__ inline float bf2f(unsigned short u) {
    union { float f; unsigned int u; } v; v.u = ((unsigned int)u) << 16;
    return v.f;
}
__device__ inline u16x8 zero8() {
    u16x8 z = {0, 0, 0, 0, 0, 0, 0, 0};
    return z;
}

// ---------------------------------------------------------------------------
// Weight convert (all 4 weights in ONE launch): fp32 [O][K] -> bf16 [K/8][O][8]
// ---------------------------------------------------------------------------
__global__ __launch_bounds__(256)
void wconv_all(const float* __restrict__ w0, const float* __restrict__ w1,
               const float* __restrict__ w2, const float* __restrict__ w3,
               unsigned short* __restrict__ d0, unsigned short* __restrict__ d1,
               unsigned short* __restrict__ d2, unsigned short* __restrict__ d3)
{
    const int bid = blockIdx.x;
    const float* W; unsigned short* WB; int O, K, base;
    if (bid < 96)       { W = w0; WB = d0; O = 768;  K = 256;  base = 0;   }
    else if (bid < 160) { W = w1; WB = d1; O = 256;  K = 512;  base = 96;  }
    else if (bid < 288) { W = w2; WB = d2; O = 1024; K = 256;  base = 160; }
    else                { W = w3; WB = d3; O = 256;  K = 1024; base = 288; }
    const int idx = (bid - base) * 256 + threadIdx.x;
    if (idx >= O * (K >> 3)) return;
    const int o = idx % O;
    const int koct = idx / O;
    u16x8 v;
#pragma unroll
    for (int j = 0; j < 8; j++) v[j] = f2bf(W[(size_t)o * K + koct * 8 + j]);
    *(u16x8*)(WB + ((size_t)koct * O + o) * 8) = v;
}

// ---------------------------------------------------------------------------
// Transpose: fp32 [b][C][1024] -> blocked bf16 [b][C/8][1024][8]
// ---------------------------------------------------------------------------
__global__ __launch_bounds__(256)
void xpose_f32_bf16(const float* __restrict__ X, unsigned short* __restrict__ XT,
                    const int C)
{
    __shared__ float tt[8][260];
    const int t = threadIdx.x;
    const int octs = C >> 3;
    const int strips = octs * 4;
    const int b = blockIdx.x / strips;
    const int rem = blockIdx.x - b * strips;
    const int coct = rem >> 2;
    const int n0 = (rem & 3) * 256;

    const int cc = t >> 5;
    const int c8 = (t & 31) * 8;
    const float* xp = X + ((size_t)b * C + coct * 8 + cc) * NPIX + n0 + c8;
    *(float4*)(&tt[cc][c8])     = *(const float4*)(xp);
    *(float4*)(&tt[cc][c8 + 4]) = *(const float4*)(xp + 4);
    __syncthreads();
    u16x8 v;
#pragma unroll
    for (int j = 0; j < 8; j++) v[j] = f2bf(tt[j][t]);
    *(u16x8*)(XT + (((size_t)b * octs + coct) * NPIX + n0 + t) * 8) = v;
}

// ---------------------------------------------------------------------------
// MFMA GEMM, DIRECT global->VGPR fragments (no LDS staging, NO main-loop
// barriers). Both operands blocked bf16 [K/8][rows][8].
//   X: [b][K/8][1024][8], W: [K/8][O][8];  Y = W·X (+ epilogue)
// Block tile BM x BN, 4 waves; BN=128: 2x2 waves; BN=64: 4x1 waves.
// Explicit 2-deep register double-buffer (named sets, static indexing).
// EPI: 0 plain, 1 BN+residual(+ACC), 2 bias+hswish.
// OMODE: 0 fp32 [c][n]; 1 bf16 [c][n] (LDS-transposed); 2 blocked bf16;
//        3 fp32 [c][n] + blocked bf16 (dual)
// ---------------------------------------------------------------------------
template<int BM, int BN, int EPI, bool ACC, int OMODE>
__global__ __launch_bounds__(256)
void gemm_direct(const unsigned short* __restrict__ X, const unsigned short* __restrict__ W,
                 float* __restrict__ Y, unsigned short* __restrict__ YB,
                 const int O, const int K,
                 const float* __restrict__ res,
                 const float* __restrict__ bng, const float* __restrict__ bnb,
                 const float* __restrict__ bnm, const float* __restrict__ bnv,
                 const float* __restrict__ bias)
{
    constexpr int TN = NPIX / BN;               // n-tiles per image
    constexpr int WAVES_N = (BN >= 128) ? 2 : 1;
    constexpr int WM = BM / (4 / WAVES_N);
    constexpr int MI = WM / 16;
    constexpr int NJ = 4;                       // wave n-extent always 64
    constexpr int TSTR = (OMODE == 1) ? (BN + 8) : (BM + 8);
    constexpr int TSZ  = (OMODE == 1) ? BM * TSTR : ((OMODE >= 2) ? BN * TSTR : 64);
    __shared__ unsigned short T[TSZ];           // epilogue transpose only

    const int t    = threadIdx.x;
    const int lane = t & 63;
    const int w    = t >> 6;

    // XCD-bijective block swizzle (all grids are multiples of 8)
    const int gx  = gridDim.x;
    const int nwg = gx * gridDim.y;
    int bid = blockIdx.y * gx + blockIdx.x;
    bid = (bid & 7) * (nwg >> 3) + (bid >> 3);
    const int bx = bid % gx;
    const int by = bid / gx;

    const int o0 = bx * BM;
    const int b  = by / TN;
    const int n0 = (by % TN) * BN;

    const int wn = (WAVES_N == 2) ? (w & 1) * 64 : 0;
    const int wo = (WAVES_N == 2) ? (w >> 1) * WM : w * WM;

    const int l16 = lane & 15;
    const int lq  = lane >> 4;

    f32x4 acc[MI][NJ];
#pragma unroll
    for (int i = 0; i < MI; i++)
#pragma unroll
        for (int j = 0; j < NJ; j++) {
            f32x4 z = {0.f, 0.f, 0.f, 0.f};
            acc[i][j] = z;
        }

    // fragment base pointers (quarter-wave lq owns k-oct kb+lq)
    // A layout: (koct*O + o)*8 ;  B layout: b-image stride K*NPIX u16,
    // within image (koct*NPIX + n)*8.
    const unsigned short* Ab = W + ((size_t)lq * O + o0 + wo + l16) * 8;
    const unsigned short* Bb = X + (size_t)b * K * NPIX
                                 + ((size_t)lq * NPIX + n0 + wn + l16) * 8;
    const size_t strideA = (size_t)O * 8;       // per k-oct
    const size_t strideB = (size_t)NPIX * 8;

    bf16x8 aA[MI], bA[NJ], aB[MI], bB[NJ];

    auto ldA = [&](bf16x8* fr, int kb) {
#pragma unroll
        for (int i = 0; i < MI; i++)
            fr[i] = *(const bf16x8*)(Ab + (size_t)kb * strideA + i * 128);
    };
    auto ldB = [&](bf16x8* fr, int kb) {
#pragma unroll
        for (int j = 0; j < NJ; j++)
            fr[j] = *(const bf16x8*)(Bb + (size_t)kb * strideB + j * 128);
    };
    auto domfma = [&](bf16x8* af, bf16x8* bf) {
#pragma unroll
        for (int i = 0; i < MI; i++)
#pragma unroll
            for (int j = 0; j < NJ; j++)
                acc[i][j] = __builtin_amdgcn_mfma_f32_16x16x32_bf16(
                    af[i], bf[j], acc[i][j], 0, 0, 0);
    };

    const int octs = K >> 3;                    // multiple of 8 (K % 64 == 0)
    ldA(aA, 0); ldB(bA, 0);
    for (int kb = 0; kb < octs; kb += 8) {
        ldA(aB, kb + 4); ldB(bB, kb + 4);       // always in range (octs % 8 == 0)
        domfma(aA, bA);
        if (kb + 8 < octs) { ldA(aA, kb + 8); ldB(bA, kb + 8); }
        domfma(aB, bB);
    }

    // epilogue. C/D: col = lane&15 (n), row = (lane>>4)*4 + reg (o)
    const int r0q = lq * 4;
    float scale[MI][4], shift[MI][4];
    if (EPI == 1) {
#pragma unroll
        for (int i = 0; i < MI; i++)
#pragma unroll
            for (int r = 0; r < 4; r++) {
                const int o = o0 + wo + i * 16 + r0q + r;
                const float inv = bng[o] / sqrtf(bnv[o] + 1e-5f);
                scale[i][r] = inv;
                shift[i][r] = bnb[o] - bnm[o] * inv;
            }
    } else if (EPI == 2) {
#pragma unroll
        for (int i = 0; i < MI; i++)
#pragma unroll
            for (int r = 0; r < 4; r++)
                shift[i][r] = bias[o0 + wo + i * 16 + r0q + r];
    }

#pragma unroll
    for (int i = 0; i < MI; i++) {
#pragma unroll
        for (int j = 0; j < NJ; j++) {
            const int nn = n0 + wn + j * 16 + l16;
            const int nl = wn + j * 16 + l16;           // n within tile
            const int ob = wo + i * 16 + r0q;           // o base within tile
            const size_t base = ((size_t)b * O + o0 + ob) * NPIX + nn;
            u16x4 p4;
#pragma unroll
            for (int r = 0; r < 4; r++) {
                const size_t off = base + (size_t)r * NPIX;
                float v = acc[i][j][r];
                if (EPI == 1) {
                    v = v * scale[i][r] + shift[i][r] + res[off];
                } else if (EPI == 2) {
                    v += shift[i][r];
                    v = v * fminf(fmaxf(v + 3.f, 0.f), 6.f) * (1.f / 6.f);
                }
                if (OMODE == 0 || OMODE == 3) {
                    if (ACC) v += Y[off];
                    Y[off] = v;
                }
                if (OMODE == 1) {
                    T[(size_t)(ob + r) * TSTR + nl] = f2bf(v);
                } else if (OMODE >= 2) {
                    p4[r] = f2bf(v);
                }
            }
            if (OMODE >= 2)
                *(u16x4*)(T + (size_t)nl * TSTR + ob) = p4;
        }
    }

    if (OMODE >= 1) {
        __syncthreads();
        constexpr int CNT = BM * BN / 2048;
        if (OMODE == 1) {
#pragma unroll
            for (int k = 0; k < CNT; k++) {
                const int idx = t + k * 256;
                const int o   = idx / (BN / 8);
                const int n8  = (idx % (BN / 8)) * 8;
                const u16x8 v = *(const u16x8*)(T + (size_t)o * TSTR + n8);
                *(u16x8*)(YB + ((size_t)b * O + o0 + o) * NPIX + n0 + n8) = v;
            }
        } else {
#pragma unroll
            for (int k = 0; k < CNT; k++) {
                const int idx = t + k * 256;
                const int oo  = idx / BN;
                const int nn  = idx % BN;
                const u16x8 v = *(const u16x8*)(T + (size_t)nn * TSTR + oo * 8);
                *(u16x8*)(YB + (((size_t)b * (O >> 3) + (o0 >> 3) + oo) * NPIX + n0 + nn) * 8) = v;
            }
        }
    }
}

// ---------------------------------------------------------------------------
// Depthwise 5x5 SAME, bf16 [c][n] in/out. fp32 LDS tile, 2 channels/block,
// register sliding window. Stride 44 padding.
// ---------------------------------------------------------------------------
__global__ __launch_bounds__(256)
void dwconv5x5_v3(const unsigned short* __restrict__ X, const float* __restrict__ Wd,
                  unsigned short* __restrict__ Y)
{
    __shared__ float tile[2 * 36 * 44];     // [ch][row 0..35][col 0..43], image+2 offset
    __shared__ float wl[64];                // [ch][25]
    const int t     = threadIdx.x;
    const int cpair = blockIdx.x % 384;
    const int b     = blockIdx.x / 384;
    const int cbase = cpair * 2;
    const unsigned short* xp = X + ((size_t)(b * 768 + cbase)) * NPIX;

    // zero whole tile (2*36*44 = 3168 floats = 792 float4)
#pragma unroll
    for (int k = 0; k < 4; k++) {
        const int i = t + k * 256;
        if (i < 792) {
            f32x4 z = {0.f, 0.f, 0.f, 0.f};
            *(f32x4*)(&tile[i * 4]) = z;
        }
    }
    if (t < 50) wl[(t / 25) * 32 + (t % 25)] = Wd[cbase * 25 + t];
    __syncthreads();

    const int ch = t >> 7;               // wave-uniform
    const int tm = t & 127;
    const int r  = tm >> 2;              // image row 0..31
    const int c8 = (tm & 3) * 8;         // image col base {0,8,16,24}

    // stage: 8 px -> fp32 interior [r+2][c8+2 .. +9]
    {
        const u16x8 v = *(const u16x8*)(xp + (size_t)ch * NPIX + r * 32 + c8);
        float* wp = &tile[ch * 1584 + (r + 2) * 44 + c8 + 2];
#pragma unroll
        for (int j = 0; j < 8; j += 2) {
            float2 f2v = make_float2(bf2f(v[j]), bf2f(v[j + 1]));
            *(float2*)(wp + j) = f2v;
        }
    }
    float wk[25];
#pragma unroll
    for (int i = 0; i < 25; i++) wk[i] = wl[ch * 32 + i];
    __syncthreads();

    float acc[8];
#pragma unroll
    for (int j = 0; j < 8; j++) acc[j] = 0.f;

#pragma unroll
    for (int ky = 0; ky < 5; ky++) {
        const float* rp = &tile[ch * 1584 + (r + ky) * 44 + c8];
        const f32x4 a = *(const f32x4*)(rp);
        const f32x4 bq = *(const f32x4*)(rp + 4);
        const f32x4 cq = *(const f32x4*)(rp + 8);
        const float in[12] = {a[0], a[1], a[2], a[3], bq[0], bq[1], bq[2], bq[3],
                              cq[0], cq[1], cq[2], cq[3]};
#pragma unroll
        for (int kx = 0; kx < 5; kx++) {
            const float wv = wk[ky * 5 + kx];
#pragma unroll
            for (int j = 0; j < 8; j++)
                acc[j] = fmaf(in[j + kx], wv, acc[j]);
        }
    }

    u16x8 o8;
#pragma unroll
    for (int j = 0; j < 8; j++) o8[j] = f2bf(acc[j]);
    *(u16x8*)(Y + ((size_t)(b * 768 + cbase + ch)) * NPIX + r * 32 + c8) = o8;
}

// ---------------------------------------------------------------------------
// Depthwise 3x3 + bias + hswish, blocked bf16 [coct][n][8] in -> blocked out.
// ---------------------------------------------------------------------------
__global__ __launch_bounds__(256)
void dwconv3x3_blk(const unsigned short* __restrict__ X, const float* __restrict__ Wd,
                   const float* __restrict__ bias, unsigned short* __restrict__ Y)
{
    __shared__ unsigned short tile[1024 * 8];
    __shared__ float wl[72];
    __shared__ float bb[8];
    const int t    = threadIdx.x;
    const int coct = blockIdx.x & 127;
    const int b    = blockIdx.x >> 7;
    const unsigned short* xp = X + ((size_t)(b * 128 + coct)) * NPIX * 8;
#pragma unroll
    for (int k = 0; k < 4; k++) {
        const int slot = t + k * 256;
        *(u16x8*)(&tile[slot * 8]) = *(const u16x8*)(xp + slot * 8);
    }
    if (t < 72) wl[t] = Wd[coct * 72 + t];
    if (t < 8)  bb[t] = bias[coct * 8 + t];
    __syncthreads();

    const int px0 = t * 4;
    const int h   = px0 >> 5;
    const int c0  = px0 & 31;

    float acc[8][4];
#pragma unroll
    for (int ch = 0; ch < 8; ch++)
#pragma unroll
        for (int j = 0; j < 4; j++) acc[ch][j] = bb[ch];

#pragma unroll
    for (int ky = 0; ky < 3; ky++) {
        const int rr = h + ky - 1;
        if (rr >= 0 && rr < 32) {
            u16x8 P[6];
#pragma unroll
            for (int m = 0; m < 6; m++) {
                const int col = c0 - 1 + m;
                const int colc = col < 0 ? 0 : (col > 31 ? 31 : col);
                u16x8 v = *(const u16x8*)(&tile[(rr * 32 + colc) * 8]);
                if (col < 0 || col > 31) v = zero8();
                P[m] = v;
            }
#pragma unroll
            for (int ch = 0; ch < 8; ch++) {
                float g[6];
#pragma unroll
                for (int m = 0; m < 6; m++) g[m] = bf2f(P[m][ch]);
#pragma unroll
                for (int j = 0; j < 4; j++)
#pragma unroll
                    for (int kx = 0; kx < 3; kx++)
                        acc[ch][j] = fmaf(g[j + kx], wl[ch * 9 + ky * 3 + kx], acc[ch][j]);
            }
        }
    }
    unsigned short* yp = Y + ((size_t)(b * 128 + coct)) * NPIX * 8 + (size_t)px0 * 8;
#pragma unroll
    for (int j = 0; j < 4; j++) {
        u16x8 o8;
#pragma unroll
        for (int ch = 0; ch < 8; ch++) {
            float v = acc[ch][j];
            v = v * fminf(fmaxf(v + 3.f, 0.f), 6.f) * (1.f / 6.f);
            o8[ch] = f2bf(v);
        }
        *(u16x8*)(yp + j * 8) = o8;
    }
}

// ---------------------------------------------------------------------------
// Grouped 32->32 1x1 (24 groups), in-place on bf16 [c][n] D.
// ---------------------------------------------------------------------------
__global__ __launch_bounds__(256)
void grouped_pw(unsigned short* __restrict__ D, const float* __restrict__ Wg)
{
    __shared__ float ws[1024];
    const int t     = threadIdx.x;
    const int blk   = blockIdx.x;          // (b*24+g)*4 + chunk
    const int chunk = blk & 3;
    const int bg    = blk >> 2;
    const int g     = bg % 24;
    const int b     = bg / 24;
    for (int i = t; i < 1024; i += 256) ws[i] = Wg[g * 1024 + i];
    __syncthreads();
    const int px = chunk * 256 + t;
    unsigned short* dp = D + ((size_t)(b * 768 + g * 32)) * NPIX + px;
    float in[32];
#pragma unroll
    for (int i = 0; i < 32; i++) in[i] = bf2f(dp[(size_t)i * NPIX]);
#pragma unroll
    for (int o = 0; o < 32; o++) {
        float s = 0.f;
#pragma unroll
        for (int i = 0; i < 32; i++) s = fmaf(ws[o * 32 + i], in[i], s);
        dp[(size_t)o * NPIX] = f2bf(s);
    }
}

// ---------------------------------------------------------------------------
// FUSED attention: one block per (b,h), 4 waves.
// Phase 1: kv[33][32] = [V;1]·relu(K)^T via MFMA (each wave a 256-px chunk),
//          cross-wave reduce into LDS kvs[1056].
// Phase 2: out[d,n] = kv·relu(Q) as a K=32 MFMA GEMM (kv rows -> A-frags in
//          bf16; Q -> 16 B-frags per wave, scalar strided loads + relu).
//          Denominator row d=32 via a 3rd A-frag; per-wave LDS broadcast.
//          Output scaled, transposed in per-wave LDS (stride 40 u16, all
//          accesses 16B-aligned), stored as blocked bf16 att[b][64][n][8].
// ---------------------------------------------------------------------------
__global__ __launch_bounds__(256)
void attn_fused(const unsigned short* __restrict__ qkv,
                const unsigned short* __restrict__ dpw,
                unsigned short* __restrict__ att)
{
    __shared__ float kvred[4][33 * 33];     // phase-1 partials (stride 33)
    __shared__ float kvs[1056];             // reduced kv
    __shared__ float dlds[4][256];          // per-wave denominators
    __shared__ unsigned short T[4][256 * 40]; // per-wave transpose (80B rows)

    const int t    = threadIdx.x;
    const int lane = t & 63;
    const int w    = t >> 6;
    const int bh   = blockIdx.x;
    const int b    = bh >> 4;
    const int h    = bh & 15;

    const unsigned short* base = (h < 8)
        ? qkv + ((size_t)(b * 768 + h * 96)) * NPIX
        : dpw + ((size_t)(b * 768 + (h - 8) * 96)) * NPIX;
    const unsigned short* qp = base;
    const unsigned short* kp = base + 32 * NPIX;
    const unsigned short* vp = base + 64 * NPIX;

    const int l16 = lane & 15;
    const int lq  = lane >> 4;
    const int ko  = lq * 8;
    const int nb  = w * 256;

    // ---------------- phase 1: kv partials ----------------
    {
        f32x4 acc[3][2];
#pragma unroll
        for (int i = 0; i < 3; i++)
#pragma unroll
            for (int j = 0; j < 2; j++) {
                f32x4 z = {0.f, 0.f, 0.f, 0.f};
                acc[i][j] = z;
            }
        bf16x8 ones;
#pragma unroll
        for (int j = 0; j < 8; j++) ones[j] = (l16 == 0) ? (short)0x3F80 : (short)0;

#pragma unroll
        for (int s = 0; s < 8; s++) {
            const int n0 = nb + s * 32 + ko;
            const bf16x8 av0 = *(const bf16x8*)(vp + (size_t)l16 * NPIX + n0);
            const bf16x8 av1 = *(const bf16x8*)(vp + (size_t)(16 + l16) * NPIX + n0);
            const u16x8 k0 = *(const u16x8*)(kp + (size_t)l16 * NPIX + n0);
            const u16x8 k1 = *(const u16x8*)(kp + (size_t)(16 + l16) * NPIX + n0);
            bf16x8 bk0, bk1;
#pragma unroll
            for (int j = 0; j < 8; j++) {
                bk0[j] = (k0[j] & 0x8000u) ? (short)0 : (short)k0[j];
                bk1[j] = (k1[j] & 0x8000u) ? (short)0 : (short)k1[j];
            }
            acc[0][0] = __builtin_amdgcn_mfma_f32_16x16x32_bf16(av0,  bk0, acc[0][0], 0, 0, 0);
            acc[0][1] = __builtin_amdgcn_mfma_f32_16x16x32_bf16(av0,  bk1, acc[0][1], 0, 0, 0);
            acc[1][0] = __builtin_amdgcn_mfma_f32_16x16x32_bf16(av1,  bk0, acc[1][0], 0, 0, 0);
            acc[1][1] = __builtin_amdgcn_mfma_f32_16x16x32_bf16(av1,  bk1, acc[1][1], 0, 0, 0);
            acc[2][0] = __builtin_amdgcn_mfma_f32_16x16x32_bf16(ones, bk0, acc[2][0], 0, 0, 0);
            acc[2][1] = __builtin_amdgcn_mfma_f32_16x16x32_bf16(ones, bk1, acc[2][1], 0, 0, 0);
        }
        const int rbase = lq * 4;
#pragma unroll
        for (int dt = 0; dt < 2; dt++)
#pragma unroll
            for (int et = 0; et < 2; et++)
#pragma unroll
                for (int r = 0; r < 4; r++)
                    kvred[w][(dt * 16 + rbase + r) * 33 + et * 16 + l16] = acc[dt][et][r];
        if (rbase == 0) {
#pragma unroll
            for (int et = 0; et < 2; et++)
                kvred[w][32 * 33 + et * 16 + l16] = acc[2][et][0];
        }
    }
    __syncthreads();
    // reduce into kvs[d*32+e]
#pragma unroll
    for (int k = 0; k < 5; k++) {
        const int idx = t + k * 256;
        if (idx < 1056) {
            const int a = (idx >> 5) * 33 + (idx & 31);
            kvs[idx] = kvred[0][a] + kvred[1][a] + kvred[2][a] + kvred[3][a];
        }
    }
    __syncthreads();

    // ---------------- phase 2: out = kv · relu(Q), K=32 ----------------
    // A-frags (per lane 8 e-contiguous at row l16): a0: d=l16, a1: d=16+l16,
    // a2: d=32 (row 0 of tile 2) else zero.
    bf16x8 a0, a1, a2;
#pragma unroll
    for (int j = 0; j < 8; j++) {
        a0[j] = (short)f2bf(kvs[l16 * 32 + ko + j]);
        a1[j] = (short)f2bf(kvs[(16 + l16) * 32 + ko + j]);
        a2[j] = (l16 == 0) ? (short)f2bf(kvs[32 * 32 + ko + j]) : (short)0;
    }
    // B-frags: 16 n-tiles of 16 px; lane (lq,l16): b[j] = relu(Q[ko+j][n])
    bf16x8 bfr[16];
    const unsigned short* qb = qp + (size_t)ko * NPIX + nb + l16;
#pragma unroll
    for (int tl = 0; tl < 16; tl++) {
        bf16x8 bf;
#pragma unroll
        for (int j = 0; j < 8; j++) {
            const unsigned short v = qb[(size_t)j * NPIX + tl * 16];
            bf[j] = (v & 0x8000u) ? (short)0 : (short)v;
        }
        bfr[tl] = bf;
    }
    // denominators (row d=32): reg0 of lanes lq==0
#pragma unroll
    for (int tl = 0; tl < 16; tl++) {
        f32x4 z = {0.f, 0.f, 0.f, 0.f};
        z = __builtin_amdgcn_mfma_f32_16x16x32_bf16(a2, bfr[tl], z, 0, 0, 0);
        if (lq == 0) dlds[w][tl * 16 + l16] = z[0];
    }
    __syncthreads();
    // main: per tile 2 MFMAs, scale, write T (per-wave region)
#pragma unroll
    for (int tl = 0; tl < 16; tl++) {
        f32x4 c0 = {0.f, 0.f, 0.f, 0.f};
        f32x4 c1 = {0.f, 0.f, 0.f, 0.f};
        c0 = __builtin_amdgcn_mfma_f32_16x16x32_bf16(a0, bfr[tl], c0, 0, 0, 0);
        c1 = __builtin_amdgcn_mfma_f32_16x16x32_bf16(a1, bfr[tl], c1, 0, 0, 0);
        const float inv = 1.f / (dlds[w][tl * 16 + l16] + 1e-15f);
        u16x4 p0, p1;
#pragma unroll
        for (int r = 0; r < 4; r++) {
            p0[r] = f2bf(c0[r] * inv);
            p1[r] = f2bf(c1[r] * inv);
        }
        unsigned short* tp = &T[w][(tl * 16 + l16) * 40];
        *(u16x4*)(tp + lq * 4)      = p0;   // d = lq*4 + r
        *(u16x4*)(tp + 16 + lq * 4) = p1;   // d = 16 + lq*4 + r
    }
    __syncthreads();
    // read T, store blocked att
#pragma unroll
    for (int k = 0; k < 16; k++) {
        const int idx = k * 64 + lane;      // 0..1023
        const int db  = idx >> 8;           // 0..3
        const int px  = idx & 255;
        const u16x8 v = *(const u16x8*)(&T[w][px * 40 + db * 8]);
        *(u16x8*)(att + (((size_t)(b * 64 + h * 4 + db)) * NPIX + nb + px) * 8) = v;
    }
}

// ---------------------------------------------------------------------------
extern "C" void kernel_launch(void* const* d_in, const int* in_sizes, int n_in,
                              void* d_out, int out_size, void* d_ws, size_t ws_size,
                              hipStream_t stream)
{
    (void)in_sizes; (void)n_in; (void)out_size; (void)ws_size;

    const float* x      = (const float*)d_in[0];
    const float* y      = (const float*)d_in[1];
    const float* qkv_w  = (const float*)d_in[2];
    const float* dw5_w  = (const float*)d_in[3];
    const float* pwg_w  = (const float*)d_in[4];
    const float* proj_w = (const float*)d_in[5];
    const float* proj_g = (const float*)d_in[6];
    const float* proj_b = (const float*)d_in[7];
    const float* proj_m = (const float*)d_in[8];
    const float* proj_v = (const float*)d_in[9];
    const float* inv_w  = (const float*)d_in[10];
    const float* inv_b  = (const float*)d_in[11];
    const float* dwc_w  = (const float*)d_in[12];
    const float* dwc_b  = (const float*)d_in[13];
    const float* pw_w   = (const float*)d_in[14];
    const float* pw_g   = (const float*)d_in[15];
    const float* pw_b   = (const float*)d_in[16];
    const float* pw_m   = (const float*)d_in[17];
    const float* pw_v   = (const float*)d_in[18];

    float* ws = (float*)d_ws;
    unsigned short* wqkv_b  = (unsigned short*)(ws + WQKV_OFF);
    unsigned short* wproj_b = (unsigned short*)(ws + WPROJ_OFF);
    unsigned short* winv_b  = (unsigned short*)(ws + WINV_OFF);
    unsigned short* wpw_b   = (unsigned short*)(ws + WPW_OFF);
    unsigned short* wxt     = (unsigned short*)(ws + XT_OFF);
    unsigned short* wqkv    = (unsigned short*)(ws + QKV_OFF);
    unsigned short* wdpw    = (unsigned short*)(ws + DPW_OFF);
    unsigned short* watt    = (unsigned short*)(ws + ATT_OFF);
    float*          wt1     = ws + T1_OFF;
    unsigned short* wt1t    = (unsigned short*)(ws + T1T_OFF);
    unsigned short* wh1t    = (unsigned short*)(ws + H1T_OFF);
    unsigned short* wh2t    = (unsigned short*)(ws + H2T_OFF);
    float* out = (float*)d_out;

    // weights -> blocked bf16 (single launch)
    wconv_all<<<dim3(416), 256, 0, stream>>>(qkv_w, proj_w, inv_w, pw_w,
                                             wqkv_b, wproj_b, winv_b, wpw_b);

    for (int blk = 0; blk < 2; blk++) {
        const float* t = (blk == 0) ? x : y;

        // --- lite_mla ---
        xpose_f32_bf16<<<dim3(2048), 256, 0, stream>>>(t, wxt, 256);
        gemm_direct<128, 128, 0, false, 1><<<dim3(6, 128), 256, 0, stream>>>(
            wxt, wqkv_b, nullptr, wqkv, 768, 256,
            nullptr, nullptr, nullptr, nullptr, nullptr, nullptr);
        dwconv5x5_v3<<<dim3(6144), 256, 0, stream>>>(wqkv, dw5_w, wdpw);
        grouped_pw<<<dim3(1536), 256, 0, stream>>>(wdpw, pwg_w);
        attn_fused<<<dim3(256), 256, 0, stream>>>(wqkv, wdpw, watt);
        gemm_direct<64, 64, 1, false, 3><<<dim3(4, 256), 256, 0, stream>>>(
            watt, wproj_b, wt1, wt1t, 256, 512,
            t, proj_g, proj_b, proj_m, proj_v, nullptr);

        // --- mbconv ---
        gemm_direct<128, 128, 2, false, 2><<<dim3(8, 128), 256, 0, stream>>>(
            wt1t, winv_b, nullptr, wh1t, 1024, 256,
            nullptr, nullptr, nullptr, nullptr, nullptr, inv_b);
        dwconv3x3_blk<<<dim3(2048), 256, 0, stream>>>(wh1t, dwc_w, dwc_b, wh2t);
        if (blk == 0) {
            gemm_direct<64, 64, 1, false, 0><<<dim3(4, 256), 256, 0, stream>>>(
                wh2t, wpw_b, out, nullptr, 256, 1024,
                wt1, pw_g, pw_b, pw_m, pw_v, nullptr);
        } else {
            gemm_direct<64, 64, 1, true, 0><<<dim3(4, 256), 256, 0, stream>>>(
                wh2t, wpw_b, out, nullptr, 256, 1024,
                wt1, pw_g, pw_b, pw_m, pw_v, nullptr);
        }
    }
}

// Round 15
// 267.284 us; speedup vs baseline: 1.4138x; 1.1681x over previous
//
#include <hip/hip_runtime.h>
#include <cstddef>

#define NPIX 1024   // H*W = 32*32

// ---------------------------------------------------------------------------
// Workspace layouts (float-slot offsets).
// BATCHED (both residual chains as images 0..31): peak 38,174,720 floats.
//   W: [0, 425984)
//   XT32 : [425984, 4620288)      32x256x1024 bf16 blocked   (dead after qkv)
//   QKV32: [4620288, 17203200)    32x768x1024 bf16 [c][n]
//   DPW32: [17203200, 29786112)
//   ATT32: [29786112, 38174720)   32x512x1024 bf16 blocked
//   T1T32: alias XT32             32x256x1024 bf16 blocked (written at proj)
//   H1T32: [4620288, 21397504)    alias QKV+DPW-head (written at inv)
//   H2T32: [21397504, 38174720)   alias DPW-tail+ATT (written at dw3x3)
// FALLBACK (per-chain, R14 layout): peak 34,045,952 floats.
// ---------------------------------------------------------------------------
static constexpr size_t WQKV_OFF  = 0;
static constexpr size_t WPROJ_OFF = 98304;
static constexpr size_t WINV_OFF  = 163840;
static constexpr size_t WPW_OFF   = 294912;
// batched
static constexpr size_t BXT_OFF   = 425984;
static constexpr size_t BQKV_OFF  = 4620288;
static constexpr size_t BDPW_OFF  = 17203200;
static constexpr size_t BATT_OFF  = 29786112;
static constexpr size_t BT1T_OFF  = 425984;     // alias XT32
static constexpr size_t BH1T_OFF  = 4620288;    // alias QKV32..
static constexpr size_t BH2T_OFF  = 21397504;   // alias DPW-tail+ATT
static constexpr size_t BATCH_NEED_F = 38174720;
// fallback (R14)
static constexpr size_t XT_OFF    = 425984;
static constexpr size_t QKV_OFF   = 2523136;
static constexpr size_t DPW_OFF   = 8814592;
static constexpr size_t ATT_OFF   = 15106048;
static constexpr size_t T1_OFF    = 21463040;
static constexpr size_t T1T_OFF   = 25657344;
static constexpr size_t H1T_OFF   = 425984;
static constexpr size_t H2T_OFF   = 25657344;

typedef __attribute__((ext_vector_type(8))) short bf16x8;
typedef __attribute__((ext_vector_type(8))) unsigned short u16x8;
typedef __attribute__((ext_vector_type(4))) unsigned short u16x4;
typedef __attribute__((ext_vector_type(4))) float f32x4;

__device__ inline unsigned short f2bf(float f) {
    union { float f; unsigned int u; } v; v.f = f;
    unsigned int u = v.u;
    u += 0x7FFFu + ((u >> 16) & 1u);        // round-to-nearest-even
    return (unsigned short)(u >> 16);
}
__device__ inline float bf2f(unsigned short u) {
    union { float f; unsigned int u; } v; v.u = ((unsigned int)u) << 16;
    return v.f;
}
__device__ inline u16x8 zero8() {
    u16x8 z = {0, 0, 0, 0, 0, 0, 0, 0};
    return z;
}

// ---------------------------------------------------------------------------
// Weight convert (all 4 weights in ONE launch): fp32 [O][K] -> bf16 [K/8][O][8]
// ---------------------------------------------------------------------------
__global__ __launch_bounds__(256)
void wconv_all(const float* __restrict__ w0, const float* __restrict__ w1,
               const float* __restrict__ w2, const float* __restrict__ w3,
               unsigned short* __restrict__ d0, unsigned short* __restrict__ d1,
               unsigned short* __restrict__ d2, unsigned short* __restrict__ d3)
{
    const int bid = blockIdx.x;
    const float* W; unsigned short* WB; int O, K, base;
    if (bid < 96)       { W = w0; WB = d0; O = 768;  K = 256;  base = 0;   }
    else if (bid < 160) { W = w1; WB = d1; O = 256;  K = 512;  base = 96;  }
    else if (bid < 288) { W = w2; WB = d2; O = 1024; K = 256;  base = 160; }
    else                { W = w3; WB = d3; O = 256;  K = 1024; base = 288; }
    const int idx = (bid - base) * 256 + threadIdx.x;
    if (idx >= O * (K >> 3)) return;
    const int o = idx % O;
    const int koct = idx / O;
    u16x8 v;
#pragma unroll
    for (int j = 0; j < 8; j++) v[j] = f2bf(W[(size_t)o * K + koct * 8 + j]);
    *(u16x8*)(WB + ((size_t)koct * O + o) * 8) = v;
}

// ---------------------------------------------------------------------------
// Transpose, dual-source: image ib<16 from X0, else X1.
// fp32 [ib][C][1024] -> blocked bf16 [ib][C/8][1024][8]
// ---------------------------------------------------------------------------
__global__ __launch_bounds__(256)
void xpose2(const float* __restrict__ X0, const float* __restrict__ X1,
            unsigned short* __restrict__ XT, const int C)
{
    __shared__ float tt[8][260];
    const int t = threadIdx.x;
    const int octs = C >> 3;
    const int strips = octs * 4;
    const int ib = blockIdx.x / strips;
    const int rem = blockIdx.x - ib * strips;
    const int coct = rem >> 2;
    const int n0 = (rem & 3) * 256;
    const float* src = (ib < 16) ? X0 + (size_t)ib * C * NPIX
                                 : X1 + (size_t)(ib - 16) * C * NPIX;
    const int cc = t >> 5;
    const int c8 = (t & 31) * 8;
    const float* xp = src + ((size_t)(coct * 8 + cc)) * NPIX + n0 + c8;
    *(float4*)(&tt[cc][c8])     = *(const float4*)(xp);
    *(float4*)(&tt[cc][c8 + 4]) = *(const float4*)(xp + 4);
    __syncthreads();
    u16x8 v;
#pragma unroll
    for (int j = 0; j < 8; j++) v[j] = f2bf(tt[j][t]);
    *(u16x8*)(XT + (((size_t)ib * octs + coct) * NPIX + n0 + t) * 8) = v;
}

// ---------------------------------------------------------------------------
// MFMA GEMM, DIRECT global->VGPR fragments (no LDS staging, no main-loop
// barriers). Operands blocked bf16 [K/8][rows][8].
// EPI: 0 plain; 1 BN + fp32 residual (res if b<16 else res2, image b&15);
//      2 bias+hswish; 3 DUAL: second K-loop over X2 into same acc, then
//      v = scale*acc + 2*shift + bf16blk res (img b) + bf16blk res (img b+16).
// OMODE: 0 fp32 [c][n] (+ACC); 1 bf16 [c][n]; 2 blocked bf16; 3 fp32+blocked.
// ---------------------------------------------------------------------------
template<int BM, int BN, int EPI, bool ACC, int OMODE>
__global__ __launch_bounds__(256)
void gemm_direct(const unsigned short* __restrict__ X, const unsigned short* __restrict__ X2,
                 const unsigned short* __restrict__ W,
                 float* __restrict__ Y, unsigned short* __restrict__ YB,
                 const int O, const int K,
                 const float* __restrict__ res, const float* __restrict__ res2,
                 const unsigned short* __restrict__ resb,
                 const float* __restrict__ bng, const float* __restrict__ bnb,
                 const float* __restrict__ bnm, const float* __restrict__ bnv,
                 const float* __restrict__ bias)
{
    constexpr int TN = NPIX / BN;
    constexpr int WAVES_N = (BN >= 128) ? 2 : 1;
    constexpr int WM = BM / (4 / WAVES_N);
    constexpr int MI = WM / 16;
    constexpr int NJ = 4;
    constexpr int TSTR = (OMODE == 1) ? (BN + 8) : (BM + 8);
    constexpr int TSZ  = (OMODE == 1) ? BM * TSTR : ((OMODE >= 2) ? BN * TSTR : 64);
    __shared__ unsigned short T[TSZ];

    const int t    = threadIdx.x;
    const int lane = t & 63;
    const int w    = t >> 6;

    // XCD-bijective block swizzle (all grids are multiples of 8)
    const int gx  = gridDim.x;
    const int nwg = gx * gridDim.y;
    int bid = blockIdx.y * gx + blockIdx.x;
    bid = (bid & 7) * (nwg >> 3) + (bid >> 3);
    const int bx = bid % gx;
    const int by = bid / gx;

    const int o0 = bx * BM;
    const int b  = by / TN;
    const int n0 = (by % TN) * BN;

    const int wn = (WAVES_N == 2) ? (w & 1) * 64 : 0;
    const int wo = (WAVES_N == 2) ? (w >> 1) * WM : w * WM;

    const int l16 = lane & 15;
    const int lq  = lane >> 4;

    f32x4 acc[MI][NJ];
#pragma unroll
    for (int i = 0; i < MI; i++)
#pragma unroll
        for (int j = 0; j < NJ; j++) {
            f32x4 z = {0.f, 0.f, 0.f, 0.f};
            acc[i][j] = z;
        }

    const unsigned short* Ab = W + ((size_t)lq * O + o0 + wo + l16) * 8;
    const size_t strideA = (size_t)O * 8;
    const size_t strideB = (size_t)NPIX * 8;
    const size_t boff = ((size_t)lq * NPIX + n0 + wn + l16) * 8;
    const int octs = K >> 3;                    // multiple of 8

    auto run_k = [&](const unsigned short* Bb) {
        bf16x8 aA[MI], bA[NJ], aB[MI], bB[NJ];
        auto ldA = [&](bf16x8* fr, int kb) {
#pragma unroll
            for (int i = 0; i < MI; i++)
                fr[i] = *(const bf16x8*)(Ab + (size_t)kb * strideA + i * 128);
        };
        auto ldB = [&](bf16x8* fr, int kb) {
#pragma unroll
            for (int j = 0; j < NJ; j++)
                fr[j] = *(const bf16x8*)(Bb + (size_t)kb * strideB + j * 128);
        };
        auto domfma = [&](bf16x8* af, bf16x8* bf) {
#pragma unroll
            for (int i = 0; i < MI; i++)
#pragma unroll
                for (int j = 0; j < NJ; j++)
                    acc[i][j] = __builtin_amdgcn_mfma_f32_16x16x32_bf16(
                        af[i], bf[j], acc[i][j], 0, 0, 0);
        };
        ldA(aA, 0); ldB(bA, 0);
        for (int kb = 0; kb < octs; kb += 8) {
            ldA(aB, kb + 4); ldB(bB, kb + 4);
            domfma(aA, bA);
            if (kb + 8 < octs) { ldA(aA, kb + 8); ldB(bA, kb + 8); }
            domfma(aB, bB);
        }
    };

    run_k(X + (size_t)b * K * NPIX + boff);
    if (EPI == 3)
        run_k(X2 + (size_t)b * K * NPIX + boff);

    // epilogue. C/D: col = lane&15 (n), row = (lane>>4)*4 + reg (o)
    const int r0q = lq * 4;
    float scale[MI][4], shift[MI][4];
    if (EPI == 1 || EPI == 3) {
#pragma unroll
        for (int i = 0; i < MI; i++)
#pragma unroll
            for (int r = 0; r < 4; r++) {
                const int o = o0 + wo + i * 16 + r0q + r;
                const float inv = bng[o] / sqrtf(bnv[o] + 1e-5f);
                scale[i][r] = inv;
                shift[i][r] = bnb[o] - bnm[o] * inv;
            }
    } else if (EPI == 2) {
#pragma unroll
        for (int i = 0; i < MI; i++)
#pragma unroll
            for (int r = 0; r < 4; r++)
                shift[i][r] = bias[o0 + wo + i * 16 + r0q + r];
    }

#pragma unroll
    for (int i = 0; i < MI; i++) {
#pragma unroll
        for (int j = 0; j < NJ; j++) {
            const int nn = n0 + wn + j * 16 + l16;
            const int nl = wn + j * 16 + l16;
            const int ob = wo + i * 16 + r0q;
            const size_t base = ((size_t)b * O + o0 + ob) * NPIX + nn;
            u16x4 r1v, r2v;
            if (EPI == 3) {
                const size_t ro = (((size_t)(b * 32 + ((o0 + ob) >> 3)) * NPIX + nn) * 8
                                   + ((o0 + ob) & 7));
                r1v = *(const u16x4*)(resb + ro);
                r2v = *(const u16x4*)(resb + (size_t)16 * 262144 + ro);
            }
            u16x4 p4;
#pragma unroll
            for (int r = 0; r < 4; r++) {
                const size_t off = base + (size_t)r * NPIX;
                float v = acc[i][j][r];
                if (EPI == 1) {
                    const float* rs = (b < 16) ? res : res2;
                    const size_t roff = ((size_t)(b & 15) * O + o0 + ob + r) * NPIX + nn;
                    v = v * scale[i][r] + shift[i][r] + rs[roff];
                } else if (EPI == 2) {
                    v += shift[i][r];
                    v = v * fminf(fmaxf(v + 3.f, 0.f), 6.f) * (1.f / 6.f);
                } else if (EPI == 3) {
                    v = v * scale[i][r] + 2.f * shift[i][r]
                        + bf2f(r1v[r]) + bf2f(r2v[r]);
                }
                if (OMODE == 0 || OMODE == 3) {
                    if (ACC) v += Y[off];
                    Y[off] = v;
                }
                if (OMODE == 1) {
                    T[(size_t)(ob + r) * TSTR + nl] = f2bf(v);
                } else if (OMODE >= 2) {
                    p4[r] = f2bf(v);
                }
            }
            if (OMODE >= 2)
                *(u16x4*)(T + (size_t)nl * TSTR + ob) = p4;
        }
    }

    if (OMODE >= 1) {
        __syncthreads();
        constexpr int CNT = BM * BN / 2048;
        if (OMODE == 1) {
#pragma unroll
            for (int k = 0; k < CNT; k++) {
                const int idx = t + k * 256;
                const int o   = idx / (BN / 8);
                const int n8  = (idx % (BN / 8)) * 8;
                const u16x8 v = *(const u16x8*)(T + (size_t)o * TSTR + n8);
                *(u16x8*)(YB + ((size_t)b * O + o0 + o) * NPIX + n0 + n8) = v;
            }
        } else {
#pragma unroll
            for (int k = 0; k < CNT; k++) {
                const int idx = t + k * 256;
                const int oo  = idx / BN;
                const int nn  = idx % BN;
                const u16x8 v = *(const u16x8*)(T + (size_t)nn * TSTR + oo * 8);
                *(u16x8*)(YB + (((size_t)b * (O >> 3) + (o0 >> 3) + oo) * NPIX + n0 + nn) * 8) = v;
            }
        }
    }
}

// ---------------------------------------------------------------------------
// Depthwise 5x5 SAME, bf16 [c][n] in/out. 2 channels/block, stride-44 fp32 LDS.
// ---------------------------------------------------------------------------
__global__ __launch_bounds__(256)
void dwconv5x5_v3(const unsigned short* __restrict__ X, const float* __restrict__ Wd,
                  unsigned short* __restrict__ Y)
{
    __shared__ float tile[2 * 36 * 44];
    __shared__ float wl[64];
    const int t     = threadIdx.x;
    const int cpair = blockIdx.x % 384;
    const int b     = blockIdx.x / 384;
    const int cbase = cpair * 2;
    const unsigned short* xp = X + ((size_t)b * 768 + cbase) * NPIX;

#pragma unroll
    for (int k = 0; k < 4; k++) {
        const int i = t + k * 256;
        if (i < 792) {
            f32x4 z = {0.f, 0.f, 0.f, 0.f};
            *(f32x4*)(&tile[i * 4]) = z;
        }
    }
    if (t < 50) wl[(t / 25) * 32 + (t % 25)] = Wd[cbase * 25 + t];
    __syncthreads();

    const int ch = t >> 7;
    const int tm = t & 127;
    const int r  = tm >> 2;
    const int c8 = (tm & 3) * 8;

    {
        const u16x8 v = *(const u16x8*)(xp + (size_t)ch * NPIX + r * 32 + c8);
        float* wp = &tile[ch * 1584 + (r + 2) * 44 + c8 + 2];
#pragma unroll
        for (int j = 0; j < 8; j += 2) {
            float2 f2v = make_float2(bf2f(v[j]), bf2f(v[j + 1]));
            *(float2*)(wp + j) = f2v;
        }
    }
    float wk[25];
#pragma unroll
    for (int i = 0; i < 25; i++) wk[i] = wl[ch * 32 + i];
    __syncthreads();

    float acc[8];
#pragma unroll
    for (int j = 0; j < 8; j++) acc[j] = 0.f;

#pragma unroll
    for (int ky = 0; ky < 5; ky++) {
        const float* rp = &tile[ch * 1584 + (r + ky) * 44 + c8];
        const f32x4 a = *(const f32x4*)(rp);
        const f32x4 bq = *(const f32x4*)(rp + 4);
        const f32x4 cq = *(const f32x4*)(rp + 8);
        const float in[12] = {a[0], a[1], a[2], a[3], bq[0], bq[1], bq[2], bq[3],
                              cq[0], cq[1], cq[2], cq[3]};
#pragma unroll
        for (int kx = 0; kx < 5; kx++) {
            const float wv = wk[ky * 5 + kx];
#pragma unroll
            for (int j = 0; j < 8; j++)
                acc[j] = fmaf(in[j + kx], wv, acc[j]);
        }
    }

    u16x8 o8;
#pragma unroll
    for (int j = 0; j < 8; j++) o8[j] = f2bf(acc[j]);
    *(u16x8*)(Y + ((size_t)b * 768 + cbase + ch) * NPIX + r * 32 + c8) = o8;
}

// ---------------------------------------------------------------------------
// Depthwise 3x3 + bias + hswish, blocked bf16 [coct][n][8] in -> blocked out.
// ---------------------------------------------------------------------------
__global__ __launch_bounds__(256)
void dwconv3x3_blk(const unsigned short* __restrict__ X, const float* __restrict__ Wd,
                   const float* __restrict__ bias, unsigned short* __restrict__ Y)
{
    __shared__ unsigned short tile[1024 * 8];
    __shared__ float wl[72];
    __shared__ float bb[8];
    const int t    = threadIdx.x;
    const int coct = blockIdx.x & 127;
    const int b    = blockIdx.x >> 7;
    const unsigned short* xp = X + ((size_t)(b * 128 + coct)) * NPIX * 8;
#pragma unroll
    for (int k = 0; k < 4; k++) {
        const int slot = t + k * 256;
        *(u16x8*)(&tile[slot * 8]) = *(const u16x8*)(xp + slot * 8);
    }
    if (t < 72) wl[t] = Wd[coct * 72 + t];
    if (t < 8)  bb[t] = bias[coct * 8 + t];
    __syncthreads();

    const int px0 = t * 4;
    const int h   = px0 >> 5;
    const int c0  = px0 & 31;

    float acc[8][4];
#pragma unroll
    for (int ch = 0; ch < 8; ch++)
#pragma unroll
        for (int j = 0; j < 4; j++) acc[ch][j] = bb[ch];

#pragma unroll
    for (int ky = 0; ky < 3; ky++) {
        const int rr = h + ky - 1;
        if (rr >= 0 && rr < 32) {
            u16x8 P[6];
#pragma unroll
            for (int m = 0; m < 6; m++) {
                const int col = c0 - 1 + m;
                const int colc = col < 0 ? 0 : (col > 31 ? 31 : col);
                u16x8 v = *(const u16x8*)(&tile[(rr * 32 + colc) * 8]);
                if (col < 0 || col > 31) v = zero8();
                P[m] = v;
            }
#pragma unroll
            for (int ch = 0; ch < 8; ch++) {
                float g[6];
#pragma unroll
                for (int m = 0; m < 6; m++) g[m] = bf2f(P[m][ch]);
#pragma unroll
                for (int j = 0; j < 4; j++)
#pragma unroll
                    for (int kx = 0; kx < 3; kx++)
                        acc[ch][j] = fmaf(g[j + kx], wl[ch * 9 + ky * 3 + kx], acc[ch][j]);
            }
        }
    }
    unsigned short* yp = Y + ((size_t)(b * 128 + coct)) * NPIX * 8 + (size_t)px0 * 8;
#pragma unroll
    for (int j = 0; j < 4; j++) {
        u16x8 o8;
#pragma unroll
        for (int ch = 0; ch < 8; ch++) {
            float v = acc[ch][j];
            v = v * fminf(fmaxf(v + 3.f, 0.f), 6.f) * (1.f / 6.f);
            o8[ch] = f2bf(v);
        }
        *(u16x8*)(yp + j * 8) = o8;
    }
}

// ---------------------------------------------------------------------------
// Grouped 32->32 1x1 (24 groups), in-place on bf16 [c][n] D.
// ---------------------------------------------------------------------------
__global__ __launch_bounds__(256)
void grouped_pw(unsigned short* __restrict__ D, const float* __restrict__ Wg)
{
    __shared__ float ws[1024];
    const int t     = threadIdx.x;
    const int blk   = blockIdx.x;
    const int chunk = blk & 3;
    const int bg    = blk >> 2;
    const int g     = bg % 24;
    const int b     = bg / 24;
    for (int i = t; i < 1024; i += 256) ws[i] = Wg[g * 1024 + i];
    __syncthreads();
    const int px = chunk * 256 + t;
    unsigned short* dp = D + ((size_t)(b * 768 + g * 32)) * NPIX + px;
    float in[32];
#pragma unroll
    for (int i = 0; i < 32; i++) in[i] = bf2f(dp[(size_t)i * NPIX]);
#pragma unroll
    for (int o = 0; o < 32; o++) {
        float s = 0.f;
#pragma unroll
        for (int i = 0; i < 32; i++) s = fmaf(ws[o * 32 + i], in[i], s);
        dp[(size_t)o * NPIX] = f2bf(s);
    }
}

// ---------------------------------------------------------------------------
// FUSED attention: one block per (b,h), 4 waves. (b up to 31 when batched.)
// ---------------------------------------------------------------------------
__global__ __launch_bounds__(256)
void attn_fused(const unsigned short* __restrict__ qkv,
                const unsigned short* __restrict__ dpw,
                unsigned short* __restrict__ att)
{
    __shared__ float kvred[4][33 * 33];
    __shared__ float kvs[1056];
    __shared__ float dlds[4][256];
    __shared__ unsigned short T[4][256 * 40];

    const int t    = threadIdx.x;
    const int lane = t & 63;
    const int w    = t >> 6;
    const int bh   = blockIdx.x;
    const int b    = bh >> 4;
    const int h    = bh & 15;

    const unsigned short* base = (h < 8)
        ? qkv + ((size_t)(b * 768 + h * 96)) * NPIX
        : dpw + ((size_t)(b * 768 + (h - 8) * 96)) * NPIX;
    const unsigned short* qp = base;
    const unsigned short* kp = base + 32 * NPIX;
    const unsigned short* vp = base + 64 * NPIX;

    const int l16 = lane & 15;
    const int lq  = lane >> 4;
    const int ko  = lq * 8;
    const int nb  = w * 256;

    // phase 1: kv partials
    {
        f32x4 acc[3][2];
#pragma unroll
        for (int i = 0; i < 3; i++)
#pragma unroll
            for (int j = 0; j < 2; j++) {
                f32x4 z = {0.f, 0.f, 0.f, 0.f};
                acc[i][j] = z;
            }
        bf16x8 ones;
#pragma unroll
        for (int j = 0; j < 8; j++) ones[j] = (l16 == 0) ? (short)0x3F80 : (short)0;

#pragma unroll
        for (int s = 0; s < 8; s++) {
            const int n0 = nb + s * 32 + ko;
            const bf16x8 av0 = *(const bf16x8*)(vp + (size_t)l16 * NPIX + n0);
            const bf16x8 av1 = *(const bf16x8*)(vp + (size_t)(16 + l16) * NPIX + n0);
            const u16x8 k0 = *(const u16x8*)(kp + (size_t)l16 * NPIX + n0);
            const u16x8 k1 = *(const u16x8*)(kp + (size_t)(16 + l16) * NPIX + n0);
            bf16x8 bk0, bk1;
#pragma unroll
            for (int j = 0; j < 8; j++) {
                bk0[j] = (k0[j] & 0x8000u) ? (short)0 : (short)k0[j];
                bk1[j] = (k1[j] & 0x8000u) ? (short)0 : (short)k1[j];
            }
            acc[0][0] = __builtin_amdgcn_mfma_f32_16x16x32_bf16(av0,  bk0, acc[0][0], 0, 0, 0);
            acc[0][1] = __builtin_amdgcn_mfma_f32_16x16x32_bf16(av0,  bk1, acc[0][1], 0, 0, 0);
            acc[1][0] = __builtin_amdgcn_mfma_f32_16x16x32_bf16(av1,  bk0, acc[1][0], 0, 0, 0);
            acc[1][1] = __builtin_amdgcn_mfma_f32_16x16x32_bf16(av1,  bk1, acc[1][1], 0, 0, 0);
            acc[2][0] = __builtin_amdgcn_mfma_f32_16x16x32_bf16(ones, bk0, acc[2][0], 0, 0, 0);
            acc[2][1] = __builtin_amdgcn_mfma_f32_16x16x32_bf16(ones, bk1, acc[2][1], 0, 0, 0);
        }
        const int rbase = lq * 4;
#pragma unroll
        for (int dt = 0; dt < 2; dt++)
#pragma unroll
            for (int et = 0; et < 2; et++)
#pragma unroll
                for (int r = 0; r < 4; r++)
                    kvred[w][(dt * 16 + rbase + r) * 33 + et * 16 + l16] = acc[dt][et][r];
        if (rbase == 0) {
#pragma unroll
            for (int et = 0; et < 2; et++)
                kvred[w][32 * 33 + et * 16 + l16] = acc[2][et][0];
        }
    }
    __syncthreads();
#pragma unroll
    for (int k = 0; k < 5; k++) {
        const int idx = t + k * 256;
        if (idx < 1056) {
            const int a = (idx >> 5) * 33 + (idx & 31);
            kvs[idx] = kvred[0][a] + kvred[1][a] + kvred[2][a] + kvred[3][a];
        }
    }
    __syncthreads();

    // phase 2: out = kv · relu(Q), K=32
    bf16x8 a0, a1, a2;
#pragma unroll
    for (int j = 0; j < 8; j++) {
        a0[j] = (short)f2bf(kvs[l16 * 32 + ko + j]);
        a1[j] = (short)f2bf(kvs[(16 + l16) * 32 + ko + j]);
        a2[j] = (l16 == 0) ? (short)f2bf(kvs[32 * 32 + ko + j]) : (short)0;
    }
    bf16x8 bfr[16];
    const unsigned short* qb = qp + (size_t)ko * NPIX + nb + l16;
#pragma unroll
    for (int tl = 0; tl < 16; tl++) {
        bf16x8 bf;
#pragma unroll
        for (int j = 0; j < 8; j++) {
            const unsigned short v = qb[(size_t)j * NPIX + tl * 16];
            bf[j] = (v & 0x8000u) ? (short)0 : (short)v;
        }
        bfr[tl] = bf;
    }
#pragma unroll
    for (int tl = 0; tl < 16; tl++) {
        f32x4 z = {0.f, 0.f, 0.f, 0.f};
        z = __builtin_amdgcn_mfma_f32_16x16x32_bf16(a2, bfr[tl], z, 0, 0, 0);
        if (lq == 0) dlds[w][tl * 16 + l16] = z[0];
    }
    __syncthreads();
#pragma unroll
    for (int tl = 0; tl < 16; tl++) {
        f32x4 c0 = {0.f, 0.f, 0.f, 0.f};
        f32x4 c1 = {0.f, 0.f, 0.f, 0.f};
        c0 = __builtin_amdgcn_mfma_f32_16x16x32_bf16(a0, bfr[tl], c0, 0, 0, 0);
        c1 = __builtin_amdgcn_mfma_f32_16x16x32_bf16(a1, bfr[tl], c1, 0, 0, 0);
        const float inv = 1.f / (dlds[w][tl * 16 + l16] + 1e-15f);
        u16x4 p0, p1;
#pragma unroll
        for (int r = 0; r < 4; r++) {
            p0[r] = f2bf(c0[r] * inv);
            p1[r] = f2bf(c1[r] * inv);
        }
        unsigned short* tp = &T[w][(tl * 16 + l16) * 40];
        *(u16x4*)(tp + lq * 4)      = p0;
        *(u16x4*)(tp + 16 + lq * 4) = p1;
    }
    __syncthreads();
#pragma unroll
    for (int k = 0; k < 16; k++) {
        const int idx = k * 64 + lane;
        const int db  = idx >> 8;
        const int px  = idx & 255;
        const u16x8 v = *(const u16x8*)(&T[w][px * 40 + db * 8]);
        *(u16x8*)(att + (((size_t)(b * 64 + h * 4 + db)) * NPIX + nb + px) * 8) = v;
    }
}

// ---------------------------------------------------------------------------
extern "C" void kernel_launch(void* const* d_in, const int* in_sizes, int n_in,
                              void* d_out, int out_size, void* d_ws, size_t ws_size,
                              hipStream_t stream)
{
    (void)in_sizes; (void)n_in; (void)out_size;

    const float* x      = (const float*)d_in[0];
    const float* y      = (const float*)d_in[1];
    const float* qkv_w  = (const float*)d_in[2];
    const float* dw5_w  = (const float*)d_in[3];
    const float* pwg_w  = (const float*)d_in[4];
    const float* proj_w = (const float*)d_in[5];
    const float* proj_g = (const float*)d_in[6];
    const float* proj_b = (const float*)d_in[7];
    const float* proj_m = (const float*)d_in[8];
    const float* proj_v = (const float*)d_in[9];
    const float* inv_w  = (const float*)d_in[10];
    const float* inv_b  = (const float*)d_in[11];
    const float* dwc_w  = (const float*)d_in[12];
    const float* dwc_b  = (const float*)d_in[13];
    const float* pw_w   = (const float*)d_in[14];
    const float* pw_g   = (const float*)d_in[15];
    const float* pw_b   = (const float*)d_in[16];
    const float* pw_m   = (const float*)d_in[17];
    const float* pw_v   = (const float*)d_in[18];

    float* ws = (float*)d_ws;
    unsigned short* wqkv_b  = (unsigned short*)(ws + WQKV_OFF);
    unsigned short* wproj_b = (unsigned short*)(ws + WPROJ_OFF);
    unsigned short* winv_b  = (unsigned short*)(ws + WINV_OFF);
    unsigned short* wpw_b   = (unsigned short*)(ws + WPW_OFF);
    float* out = (float*)d_out;

    wconv_all<<<dim3(416), 256, 0, stream>>>(qkv_w, proj_w, inv_w, pw_w,
                                             wqkv_b, wproj_b, winv_b, wpw_b);

    if (ws_size >= (size_t)BATCH_NEED_F * 4ull) {
        // ---------------- batched path: both chains as images 0..31 ----------
        unsigned short* bxt  = (unsigned short*)(ws + BXT_OFF);
        unsigned short* bqkv = (unsigned short*)(ws + BQKV_OFF);
        unsigned short* bdpw = (unsigned short*)(ws + BDPW_OFF);
        unsigned short* batt = (unsigned short*)(ws + BATT_OFF);
        unsigned short* bt1t = (unsigned short*)(ws + BT1T_OFF);
        unsigned short* bh1t = (unsigned short*)(ws + BH1T_OFF);
        unsigned short* bh2t = (unsigned short*)(ws + BH2T_OFF);

        xpose2<<<dim3(4096), 256, 0, stream>>>(x, y, bxt, 256);
        gemm_direct<128, 128, 0, false, 1><<<dim3(6, 256), 256, 0, stream>>>(
            bxt, nullptr, wqkv_b, nullptr, bqkv, 768, 256,
            nullptr, nullptr, nullptr, nullptr, nullptr, nullptr, nullptr, nullptr);
        dwconv5x5_v3<<<dim3(12288), 256, 0, stream>>>(bqkv, dw5_w, bdpw);
        grouped_pw<<<dim3(3072), 256, 0, stream>>>(bdpw, pwg_w);
        attn_fused<<<dim3(512), 256, 0, stream>>>(bqkv, bdpw, batt);
        gemm_direct<64, 64, 1, false, 2><<<dim3(4, 512), 256, 0, stream>>>(
            batt, nullptr, wproj_b, nullptr, bt1t, 256, 512,
            x, y, nullptr, proj_g, proj_b, proj_m, proj_v, nullptr);
        gemm_direct<128, 128, 2, false, 2><<<dim3(8, 256), 256, 0, stream>>>(
            bt1t, nullptr, winv_b, nullptr, bh1t, 1024, 256,
            nullptr, nullptr, nullptr, nullptr, nullptr, nullptr, nullptr, inv_b);
        dwconv3x3_blk<<<dim3(4096), 256, 0, stream>>>(bh1t, dwc_w, dwc_b, bh2t);
        gemm_direct<64, 64, 3, false, 0><<<dim3(4, 256), 256, 0, stream>>>(
            bh2t, bh2t + (size_t)16 * 1024 * 1024, wpw_b, out, nullptr, 256, 1024,
            nullptr, nullptr, bt1t, pw_g, pw_b, pw_m, pw_v, nullptr);
    } else {
        // ---------------- fallback: per-chain (R14 structure) ----------------
        unsigned short* wxt  = (unsigned short*)(ws + XT_OFF);
        unsigned short* wqkv = (unsigned short*)(ws + QKV_OFF);
        unsigned short* wdpw = (unsigned short*)(ws + DPW_OFF);
        unsigned short* watt = (unsigned short*)(ws + ATT_OFF);
        float*          wt1  = ws + T1_OFF;
        unsigned short* wt1t = (unsigned short*)(ws + T1T_OFF);
        unsigned short* wh1t = (unsigned short*)(ws + H1T_OFF);
        unsigned short* wh2t = (unsigned short*)(ws + H2T_OFF);

        for (int blk = 0; blk < 2; blk++) {
            const float* t = (blk == 0) ? x : y;
            xpose2<<<dim3(2048), 256, 0, stream>>>(t, t, wxt, 256);
            gemm_direct<128, 128, 0, false, 1><<<dim3(6, 128), 256, 0, stream>>>(
                wxt, nullptr, wqkv_b, nullptr, wqkv, 768, 256,
                nullptr, nullptr, nullptr, nullptr, nullptr, nullptr, nullptr, nullptr);
            dwconv5x5_v3<<<dim3(6144), 256, 0, stream>>>(wqkv, dw5_w, wdpw);
            grouped_pw<<<dim3(1536), 256, 0, stream>>>(wdpw, pwg_w);
            attn_fused<<<dim3(256), 256, 0, stream>>>(wqkv, wdpw, watt);
            gemm_direct<64, 64, 1, false, 3><<<dim3(4, 256), 256, 0, stream>>>(
                watt, nullptr, wproj_b, wt1, wt1t, 256, 512,
                t, t, nullptr, proj_g, proj_b, proj_m, proj_v, nullptr);
            gemm_direct<128, 128, 2, false, 2><<<dim3(8, 128), 256, 0, stream>>>(
                wt1t, nullptr, winv_b, nullptr, wh1t, 1024, 256,
                nullptr, nullptr, nullptr, nullptr, nullptr, nullptr, nullptr, inv_b);
            dwconv3x3_blk<<<dim3(2048), 256, 0, stream>>>(wh1t, dwc_w, dwc_b, wh2t);
            if (blk == 0) {
                gemm_direct<64, 64, 1, false, 0><<<dim3(4, 256), 256, 0, stream>>>(
                    wh2t, nullptr, wpw_b, out, nullptr, 256, 1024,
                    wt1, wt1, nullptr, pw_g, pw_b, pw_m, pw_v, nullptr);
            } else {
                gemm_direct<64, 64, 1, true, 0><<<dim3(4, 256), 256, 0, stream>>>(
                    wh2t, nullptr, wpw_b, out, nullptr, 256, 1024,
                    wt1, wt1, nullptr, pw_g, pw_b, pw_m, pw_v, nullptr);
            }
        }
    }
}

// Round 16
// 263.478 us; speedup vs baseline: 1.4342x; 1.0144x over previous
//
#include <hip/hip_runtime.h>
#include <cstddef>

#define NPIX 1024   // H*W = 32*32

// ---------------------------------------------------------------------------
// Workspace layouts (float-slot offsets).
// BATCHED (both residual chains as images 0..31): peak 38,174,720 floats.
// FALLBACK (per-chain, R14 layout): peak 34,045,952 floats.
// ---------------------------------------------------------------------------
static constexpr size_t WQKV_OFF  = 0;
static constexpr size_t WPROJ_OFF = 98304;
static constexpr size_t WINV_OFF  = 163840;
static constexpr size_t WPW_OFF   = 294912;
// batched
static constexpr size_t BXT_OFF   = 425984;
static constexpr size_t BQKV_OFF  = 4620288;
static constexpr size_t BDPW_OFF  = 17203200;
static constexpr size_t BATT_OFF  = 29786112;
static constexpr size_t BT1T_OFF  = 425984;     // alias XT32
static constexpr size_t BH1T_OFF  = 4620288;    // alias QKV32..
static constexpr size_t BH2T_OFF  = 21397504;   // alias DPW-tail+ATT
static constexpr size_t BATCH_NEED_F = 38174720;
// fallback (R14)
static constexpr size_t XT_OFF    = 425984;
static constexpr size_t QKV_OFF   = 2523136;
static constexpr size_t DPW_OFF   = 8814592;
static constexpr size_t ATT_OFF   = 15106048;
static constexpr size_t T1_OFF    = 21463040;
static constexpr size_t T1T_OFF   = 25657344;
static constexpr size_t H1T_OFF   = 425984;
static constexpr size_t H2T_OFF   = 25657344;

typedef __attribute__((ext_vector_type(8))) short bf16x8;
typedef __attribute__((ext_vector_type(8))) unsigned short u16x8;
typedef __attribute__((ext_vector_type(4))) unsigned short u16x4;
typedef __attribute__((ext_vector_type(4))) float f32x4;

__device__ inline unsigned short f2bf(float f) {
    union { float f; unsigned int u; } v; v.f = f;
    unsigned int u = v.u;
    u += 0x7FFFu + ((u >> 16) & 1u);        // round-to-nearest-even
    return (unsigned short)(u >> 16);
}
__device__ inline float bf2f(unsigned short u) {
    union { float f; unsigned int u; } v; v.u = ((unsigned int)u) << 16;
    return v.f;
}
__device__ inline u16x8 zero8() {
    u16x8 z = {0, 0, 0, 0, 0, 0, 0, 0};
    return z;
}
__device__ inline int pswz(int p) { return p ^ ((p >> 3) & 7); }   // 16B-slot swizzle

// ---------------------------------------------------------------------------
// Weight convert (all 4 weights in ONE launch): fp32 [O][K] -> bf16 [K/8][O][8]
// ---------------------------------------------------------------------------
__global__ __launch_bounds__(256)
void wconv_all(const float* __restrict__ w0, const float* __restrict__ w1,
               const float* __restrict__ w2, const float* __restrict__ w3,
               unsigned short* __restrict__ d0, unsigned short* __restrict__ d1,
               unsigned short* __restrict__ d2, unsigned short* __restrict__ d3)
{
    const int bid = blockIdx.x;
    const float* W; unsigned short* WB; int O, K, base;
    if (bid < 96)       { W = w0; WB = d0; O = 768;  K = 256;  base = 0;   }
    else if (bid < 160) { W = w1; WB = d1; O = 256;  K = 512;  base = 96;  }
    else if (bid < 288) { W = w2; WB = d2; O = 1024; K = 256;  base = 160; }
    else                { W = w3; WB = d3; O = 256;  K = 1024; base = 288; }
    const int idx = (bid - base) * 256 + threadIdx.x;
    if (idx >= O * (K >> 3)) return;
    const int o = idx % O;
    const int koct = idx / O;
    u16x8 v;
#pragma unroll
    for (int j = 0; j < 8; j++) v[j] = f2bf(W[(size_t)o * K + koct * 8 + j]);
    *(u16x8*)(WB + ((size_t)koct * O + o) * 8) = v;
}

// ---------------------------------------------------------------------------
// Transpose, dual-source: image ib<16 from X0, else X1.
// ---------------------------------------------------------------------------
__global__ __launch_bounds__(256)
void xpose2(const float* __restrict__ X0, const float* __restrict__ X1,
            unsigned short* __restrict__ XT, const int C)
{
    __shared__ float tt[8][260];
    const int t = threadIdx.x;
    const int octs = C >> 3;
    const int strips = octs * 4;
    const int ib = blockIdx.x / strips;
    const int rem = blockIdx.x - ib * strips;
    const int coct = rem >> 2;
    const int n0 = (rem & 3) * 256;
    const float* src = (ib < 16) ? X0 + (size_t)ib * C * NPIX
                                 : X1 + (size_t)(ib - 16) * C * NPIX;
    const int cc = t >> 5;
    const int c8 = (t & 31) * 8;
    const float* xp = src + ((size_t)(coct * 8 + cc)) * NPIX + n0 + c8;
    *(float4*)(&tt[cc][c8])     = *(const float4*)(xp);
    *(float4*)(&tt[cc][c8 + 4]) = *(const float4*)(xp + 4);
    __syncthreads();
    u16x8 v;
#pragma unroll
    for (int j = 0; j < 8; j++) v[j] = f2bf(tt[j][t]);
    *(u16x8*)(XT + (((size_t)ib * octs + coct) * NPIX + n0 + t) * 8) = v;
}

// ---------------------------------------------------------------------------
// MFMA GEMM, DIRECT global->VGPR fragments (no LDS staging, no main-loop
// barriers). Operands blocked bf16 [K/8][rows][8].
// EPI: 0 plain; 1 BN + fp32 residual (res if b<16 else res2, image b&15);
//      2 bias+hswish; 3 DUAL: INTERLEAVED second K-stream X2 into acc2
//      (shared A-frags -> 2x loads in flight + 2x MFMA per prefetch window),
//      then v = scale*(acc+acc2) + 2*shift + bf16blk res (b) + res (b+16).
// OMODE: 0 fp32 [c][n] (+ACC); 1 bf16 [c][n]; 2 blocked bf16; 3 fp32+blocked.
// ---------------------------------------------------------------------------
template<int BM, int BN, int EPI, bool ACC, int OMODE>
__global__ __launch_bounds__(256)
void gemm_direct(const unsigned short* __restrict__ X, const unsigned short* __restrict__ X2,
                 const unsigned short* __restrict__ W,
                 float* __restrict__ Y, unsigned short* __restrict__ YB,
                 const int O, const int K,
                 const float* __restrict__ res, const float* __restrict__ res2,
                 const unsigned short* __restrict__ resb,
                 const float* __restrict__ bng, const float* __restrict__ bnb,
                 const float* __restrict__ bnm, const float* __restrict__ bnv,
                 const float* __restrict__ bias)
{
    constexpr int TN = NPIX / BN;
    constexpr int WAVES_N = (BN >= 128) ? 2 : 1;
    constexpr int WM = BM / (4 / WAVES_N);
    constexpr int MI = WM / 16;
    constexpr int NJ = 4;
    constexpr int TSTR = (OMODE == 1) ? (BN + 8) : (BM + 8);
    constexpr int TSZ  = (OMODE == 1) ? BM * TSTR : ((OMODE >= 2) ? BN * TSTR : 64);
    __shared__ unsigned short T[TSZ];

    const int t    = threadIdx.x;
    const int lane = t & 63;
    const int w    = t >> 6;

    // XCD-bijective block swizzle (all grids are multiples of 8)
    const int gx  = gridDim.x;
    const int nwg = gx * gridDim.y;
    int bid = blockIdx.y * gx + blockIdx.x;
    bid = (bid & 7) * (nwg >> 3) + (bid >> 3);
    const int bx = bid % gx;
    const int by = bid / gx;

    const int o0 = bx * BM;
    const int b  = by / TN;
    const int n0 = (by % TN) * BN;

    const int wn = (WAVES_N == 2) ? (w & 1) * 64 : 0;
    const int wo = (WAVES_N == 2) ? (w >> 1) * WM : w * WM;

    const int l16 = lane & 15;
    const int lq  = lane >> 4;

    f32x4 acc[MI][NJ];
    f32x4 acc2[MI][NJ];
#pragma unroll
    for (int i = 0; i < MI; i++)
#pragma unroll
        for (int j = 0; j < NJ; j++) {
            f32x4 z = {0.f, 0.f, 0.f, 0.f};
            acc[i][j] = z;
            acc2[i][j] = z;
        }

    const unsigned short* Ab = W + ((size_t)lq * O + o0 + wo + l16) * 8;
    const size_t strideA = (size_t)O * 8;
    const size_t strideB = (size_t)NPIX * 8;
    const size_t boff = ((size_t)lq * NPIX + n0 + wn + l16) * 8;
    const int octs = K >> 3;                    // multiple of 8

    auto ldA_ = [&](bf16x8* fr, int kb) {
#pragma unroll
        for (int i = 0; i < MI; i++)
            fr[i] = *(const bf16x8*)(Ab + (size_t)kb * strideA + i * 128);
    };
    auto ldB_ = [&](bf16x8* fr, const unsigned short* Bb, int kb) {
#pragma unroll
        for (int j = 0; j < NJ; j++)
            fr[j] = *(const bf16x8*)(Bb + (size_t)kb * strideB + j * 128);
    };
    auto domfma_ = [&](f32x4 (&ac)[MI][NJ], bf16x8* af, bf16x8* bf) {
#pragma unroll
        for (int i = 0; i < MI; i++)
#pragma unroll
            for (int j = 0; j < NJ; j++)
                ac[i][j] = __builtin_amdgcn_mfma_f32_16x16x32_bf16(
                    af[i], bf[j], ac[i][j], 0, 0, 0);
    };

    if (EPI != 3) {
        const unsigned short* Bb = X + (size_t)b * K * NPIX + boff;
        bf16x8 aA[MI], bA[NJ], aB[MI], bB[NJ];
        ldA_(aA, 0); ldB_(bA, Bb, 0);
        for (int kb = 0; kb < octs; kb += 8) {
            ldA_(aB, kb + 4); ldB_(bB, Bb, kb + 4);
            domfma_(acc, aA, bA);
            if (kb + 8 < octs) { ldA_(aA, kb + 8); ldB_(bA, Bb, kb + 8); }
            domfma_(acc, aB, bB);
        }
    } else {
        // interleaved dual stream, shared A
        const unsigned short* B1 = X  + (size_t)b * K * NPIX + boff;
        const unsigned short* B2 = X2 + (size_t)b * K * NPIX + boff;
        bf16x8 aA[MI], aB[MI], b1A[NJ], b1B[NJ], b2A[NJ], b2B[NJ];
        ldA_(aA, 0); ldB_(b1A, B1, 0); ldB_(b2A, B2, 0);
        for (int kb = 0; kb < octs; kb += 8) {
            ldA_(aB, kb + 4);
            ldB_(b1B, B1, kb + 4); ldB_(b2B, B2, kb + 4);
            domfma_(acc,  aA, b1A);
            domfma_(acc2, aA, b2A);
            if (kb + 8 < octs) {
                ldA_(aA, kb + 8);
                ldB_(b1A, B1, kb + 8); ldB_(b2A, B2, kb + 8);
            }
            domfma_(acc,  aB, b1B);
            domfma_(acc2, aB, b2B);
        }
    }

    // epilogue. C/D: col = lane&15 (n), row = (lane>>4)*4 + reg (o)
    const int r0q = lq * 4;
    float scale[MI][4], shift[MI][4];
    if (EPI == 1 || EPI == 3) {
#pragma unroll
        for (int i = 0; i < MI; i++)
#pragma unroll
            for (int r = 0; r < 4; r++) {
                const int o = o0 + wo + i * 16 + r0q + r;
                const float inv = bng[o] / sqrtf(bnv[o] + 1e-5f);
                scale[i][r] = inv;
                shift[i][r] = bnb[o] - bnm[o] * inv;
            }
    } else if (EPI == 2) {
#pragma unroll
        for (int i = 0; i < MI; i++)
#pragma unroll
            for (int r = 0; r < 4; r++)
                shift[i][r] = bias[o0 + wo + i * 16 + r0q + r];
    }

#pragma unroll
    for (int i = 0; i < MI; i++) {
#pragma unroll
        for (int j = 0; j < NJ; j++) {
            const int nn = n0 + wn + j * 16 + l16;
            const int nl = wn + j * 16 + l16;
            const int ob = wo + i * 16 + r0q;
            const size_t base = ((size_t)b * O + o0 + ob) * NPIX + nn;
            u16x4 r1v, r2v;
            if (EPI == 3) {
                const size_t ro = (((size_t)(b * 32 + ((o0 + ob) >> 3)) * NPIX + nn) * 8
                                   + ((o0 + ob) & 7));
                r1v = *(const u16x4*)(resb + ro);
                r2v = *(const u16x4*)(resb + (size_t)16 * 262144 + ro);
            }
            u16x4 p4;
#pragma unroll
            for (int r = 0; r < 4; r++) {
                const size_t off = base + (size_t)r * NPIX;
                float v = acc[i][j][r];
                if (EPI == 1) {
                    const float* rs = (b < 16) ? res : res2;
                    const size_t roff = ((size_t)(b & 15) * O + o0 + ob + r) * NPIX + nn;
                    v = v * scale[i][r] + shift[i][r] + rs[roff];
                } else if (EPI == 2) {
                    v += shift[i][r];
                    v = v * fminf(fmaxf(v + 3.f, 0.f), 6.f) * (1.f / 6.f);
                } else if (EPI == 3) {
                    v = (v + acc2[i][j][r]) * scale[i][r] + 2.f * shift[i][r]
                        + bf2f(r1v[r]) + bf2f(r2v[r]);
                }
                if (OMODE == 0 || OMODE == 3) {
                    if (ACC) v += Y[off];
                    Y[off] = v;
                }
                if (OMODE == 1) {
                    T[(size_t)(ob + r) * TSTR + nl] = f2bf(v);
                } else if (OMODE >= 2) {
                    p4[r] = f2bf(v);
                }
            }
            if (OMODE >= 2)
                *(u16x4*)(T + (size_t)nl * TSTR + ob) = p4;
        }
    }

    if (OMODE >= 1) {
        __syncthreads();
        constexpr int CNT = BM * BN / 2048;
        if (OMODE == 1) {
#pragma unroll
            for (int k = 0; k < CNT; k++) {
                const int idx = t + k * 256;
                const int o   = idx / (BN / 8);
                const int n8  = (idx % (BN / 8)) * 8;
                const u16x8 v = *(const u16x8*)(T + (size_t)o * TSTR + n8);
                *(u16x8*)(YB + ((size_t)b * O + o0 + o) * NPIX + n0 + n8) = v;
            }
        } else {
#pragma unroll
            for (int k = 0; k < CNT; k++) {
                const int idx = t + k * 256;
                const int oo  = idx / BN;
                const int nn  = idx % BN;
                const u16x8 v = *(const u16x8*)(T + (size_t)nn * TSTR + oo * 8);
                *(u16x8*)(YB + (((size_t)b * (O >> 3) + (o0 >> 3) + oo) * NPIX + n0 + nn) * 8) = v;
            }
        }
    }
}

// ---------------------------------------------------------------------------
// Depthwise 5x5 SAME, bf16 [c][n] in/out. 2 channels/block, stride-44 fp32 LDS.
// ---------------------------------------------------------------------------
__global__ __launch_bounds__(256)
void dwconv5x5_v3(const unsigned short* __restrict__ X, const float* __restrict__ Wd,
                  unsigned short* __restrict__ Y)
{
    __shared__ float tile[2 * 36 * 44];
    __shared__ float wl[64];
    const int t     = threadIdx.x;
    const int cpair = blockIdx.x % 384;
    const int b     = blockIdx.x / 384;
    const int cbase = cpair * 2;
    const unsigned short* xp = X + ((size_t)b * 768 + cbase) * NPIX;

#pragma unroll
    for (int k = 0; k < 4; k++) {
        const int i = t + k * 256;
        if (i < 792) {
            f32x4 z = {0.f, 0.f, 0.f, 0.f};
            *(f32x4*)(&tile[i * 4]) = z;
        }
    }
    if (t < 50) wl[(t / 25) * 32 + (t % 25)] = Wd[cbase * 25 + t];
    __syncthreads();

    const int ch = t >> 7;
    const int tm = t & 127;
    const int r  = tm >> 2;
    const int c8 = (tm & 3) * 8;

    {
        const u16x8 v = *(const u16x8*)(xp + (size_t)ch * NPIX + r * 32 + c8);
        float* wp = &tile[ch * 1584 + (r + 2) * 44 + c8 + 2];
#pragma unroll
        for (int j = 0; j < 8; j += 2) {
            float2 f2v = make_float2(bf2f(v[j]), bf2f(v[j + 1]));
            *(float2*)(wp + j) = f2v;
        }
    }
    float wk[25];
#pragma unroll
    for (int i = 0; i < 25; i++) wk[i] = wl[ch * 32 + i];
    __syncthreads();

    float acc[8];
#pragma unroll
    for (int j = 0; j < 8; j++) acc[j] = 0.f;

#pragma unroll
    for (int ky = 0; ky < 5; ky++) {
        const float* rp = &tile[ch * 1584 + (r + ky) * 44 + c8];
        const f32x4 a = *(const f32x4*)(rp);
        const f32x4 bq = *(const f32x4*)(rp + 4);
        const f32x4 cq = *(const f32x4*)(rp + 8);
        const float in[12] = {a[0], a[1], a[2], a[3], bq[0], bq[1], bq[2], bq[3],
                              cq[0], cq[1], cq[2], cq[3]};
#pragma unroll
        for (int kx = 0; kx < 5; kx++) {
            const float wv = wk[ky * 5 + kx];
#pragma unroll
            for (int j = 0; j < 8; j++)
                acc[j] = fmaf(in[j + kx], wv, acc[j]);
        }
    }

    u16x8 o8;
#pragma unroll
    for (int j = 0; j < 8; j++) o8[j] = f2bf(acc[j]);
    *(u16x8*)(Y + ((size_t)b * 768 + cbase + ch) * NPIX + r * 32 + c8) = o8;
}

// ---------------------------------------------------------------------------
// Depthwise 3x3 + bias + hswish, blocked bf16 in/out.
// LDS pixel-slot swizzle sp(p) = p ^ ((p>>3)&7) on BOTH write and read:
// breaks the 2-distinct-(p%8) read pattern (was ~16-way conflict).
// ---------------------------------------------------------------------------
__global__ __launch_bounds__(256)
void dwconv3x3_blk(const unsigned short* __restrict__ X, const float* __restrict__ Wd,
                   const float* __restrict__ bias, unsigned short* __restrict__ Y)
{
    __shared__ unsigned short tile[1024 * 8];
    __shared__ float wl[72];
    __shared__ float bb[8];
    const int t    = threadIdx.x;
    const int coct = blockIdx.x & 127;
    const int b    = blockIdx.x >> 7;
    const unsigned short* xp = X + ((size_t)(b * 128 + coct)) * NPIX * 8;
#pragma unroll
    for (int k = 0; k < 4; k++) {
        const int p = t + k * 256;
        *(u16x8*)(&tile[pswz(p) * 8]) = *(const u16x8*)(xp + p * 8);
    }
    if (t < 72) wl[t] = Wd[coct * 72 + t];
    if (t < 8)  bb[t] = bias[coct * 8 + t];
    __syncthreads();

    const int px0 = t * 4;
    const int h   = px0 >> 5;
    const int c0  = px0 & 31;

    float acc[8][4];
#pragma unroll
    for (int ch = 0; ch < 8; ch++)
#pragma unroll
        for (int j = 0; j < 4; j++) acc[ch][j] = bb[ch];

#pragma unroll
    for (int ky = 0; ky < 3; ky++) {
        const int rr = h + ky - 1;
        if (rr >= 0 && rr < 32) {
            u16x8 P[6];
#pragma unroll
            for (int m = 0; m < 6; m++) {
                const int col = c0 - 1 + m;
                const int colc = col < 0 ? 0 : (col > 31 ? 31 : col);
                u16x8 v = *(const u16x8*)(&tile[pswz(rr * 32 + colc) * 8]);
                if (col < 0 || col > 31) v = zero8();
                P[m] = v;
            }
#pragma unroll
            for (int ch = 0; ch < 8; ch++) {
                float g[6];
#pragma unroll
                for (int m = 0; m < 6; m++) g[m] = bf2f(P[m][ch]);
#pragma unroll
                for (int j = 0; j < 4; j++)
#pragma unroll
                    for (int kx = 0; kx < 3; kx++)
                        acc[ch][j] = fmaf(g[j + kx], wl[ch * 9 + ky * 3 + kx], acc[ch][j]);
            }
        }
    }
    unsigned short* yp = Y + ((size_t)(b * 128 + coct)) * NPIX * 8 + (size_t)px0 * 8;
#pragma unroll
    for (int j = 0; j < 4; j++) {
        u16x8 o8;
#pragma unroll
        for (int ch = 0; ch < 8; ch++) {
            float v = acc[ch][j];
            v = v * fminf(fmaxf(v + 3.f, 0.f), 6.f) * (1.f / 6.f);
            o8[ch] = f2bf(v);
        }
        *(u16x8*)(yp + j * 8) = o8;
    }
}

// ---------------------------------------------------------------------------
// Grouped 32->32 1x1 (24 groups), in-place on bf16 [c][n] D.
// ---------------------------------------------------------------------------
__global__ __launch_bounds__(256)
void grouped_pw(unsigned short* __restrict__ D, const float* __restrict__ Wg)
{
    __shared__ float ws[1024];
    const int t     = threadIdx.x;
    const int blk   = blockIdx.x;
    const int chunk = blk & 3;
    const int bg    = blk >> 2;
    const int g     = bg % 24;
    const int b     = bg / 24;
    for (int i = t; i < 1024; i += 256) ws[i] = Wg[g * 1024 + i];
    __syncthreads();
    const int px = chunk * 256 + t;
    unsigned short* dp = D + ((size_t)(b * 768 + g * 32)) * NPIX + px;
    float in[32];
#pragma unroll
    for (int i = 0; i < 32; i++) in[i] = bf2f(dp[(size_t)i * NPIX]);
#pragma unroll
    for (int o = 0; o < 32; o++) {
        float s = 0.f;
#pragma unroll
        for (int i = 0; i < 32; i++) s = fmaf(ws[o * 32 + i], in[i], s);
        dp[(size_t)o * NPIX] = f2bf(s);
    }
}

// ---------------------------------------------------------------------------
// FUSED attention: one block per (b,h), 4 waves. (b up to 31 when batched.)
// ---------------------------------------------------------------------------
__global__ __launch_bounds__(256)
void attn_fused(const unsigned short* __restrict__ qkv,
                const unsigned short* __restrict__ dpw,
                unsigned short* __restrict__ att)
{
    __shared__ float kvred[4][33 * 33];
    __shared__ float kvs[1056];
    __shared__ float dlds[4][256];
    __shared__ unsigned short T[4][256 * 40];

    const int t    = threadIdx.x;
    const int lane = t & 63;
    const int w    = t >> 6;
    const int bh   = blockIdx.x;
    const int b    = bh >> 4;
    const int h    = bh & 15;

    const unsigned short* base = (h < 8)
        ? qkv + ((size_t)(b * 768 + h * 96)) * NPIX
        : dpw + ((size_t)(b * 768 + (h - 8) * 96)) * NPIX;
    const unsigned short* qp = base;
    const unsigned short* kp = base + 32 * NPIX;
    const unsigned short* vp = base + 64 * NPIX;

    const int l16 = lane & 15;
    const int lq  = lane >> 4;
    const int ko  = lq * 8;
    const int nb  = w * 256;

    // phase 1: kv partials
    {
        f32x4 acc[3][2];
#pragma unroll
        for (int i = 0; i < 3; i++)
#pragma unroll
            for (int j = 0; j < 2; j++) {
                f32x4 z = {0.f, 0.f, 0.f, 0.f};
                acc[i][j] = z;
            }
        bf16x8 ones;
#pragma unroll
        for (int j = 0; j < 8; j++) ones[j] = (l16 == 0) ? (short)0x3F80 : (short)0;

#pragma unroll
        for (int s = 0; s < 8; s++) {
            const int n0 = nb + s * 32 + ko;
            const bf16x8 av0 = *(const bf16x8*)(vp + (size_t)l16 * NPIX + n0);
            const bf16x8 av1 = *(const bf16x8*)(vp + (size_t)(16 + l16) * NPIX + n0);
            const u16x8 k0 = *(const u16x8*)(kp + (size_t)l16 * NPIX + n0);
            const u16x8 k1 = *(const u16x8*)(kp + (size_t)(16 + l16) * NPIX + n0);
            bf16x8 bk0, bk1;
#pragma unroll
            for (int j = 0; j < 8; j++) {
                bk0[j] = (k0[j] & 0x8000u) ? (short)0 : (short)k0[j];
                bk1[j] = (k1[j] & 0x8000u) ? (short)0 : (short)k1[j];
            }
            acc[0][0] = __builtin_amdgcn_mfma_f32_16x16x32_bf16(av0,  bk0, acc[0][0], 0, 0, 0);
            acc[0][1] = __builtin_amdgcn_mfma_f32_16x16x32_bf16(av0,  bk1, acc[0][1], 0, 0, 0);
            acc[1][0] = __builtin_amdgcn_mfma_f32_16x16x32_bf16(av1,  bk0, acc[1][0], 0, 0, 0);
            acc[1][1] = __builtin_amdgcn_mfma_f32_16x16x32_bf16(av1,  bk1, acc[1][1], 0, 0, 0);
            acc[2][0] = __builtin_amdgcn_mfma_f32_16x16x32_bf16(ones, bk0, acc[2][0], 0, 0, 0);
            acc[2][1] = __builtin_amdgcn_mfma_f32_16x16x32_bf16(ones, bk1, acc[2][1], 0, 0, 0);
        }
        const int rbase = lq * 4;
#pragma unroll
        for (int dt = 0; dt < 2; dt++)
#pragma unroll
            for (int et = 0; et < 2; et++)
#pragma unroll
                for (int r = 0; r < 4; r++)
                    kvred[w][(dt * 16 + rbase + r) * 33 + et * 16 + l16] = acc[dt][et][r];
        if (rbase == 0) {
#pragma unroll
            for (int et = 0; et < 2; et++)
                kvred[w][32 * 33 + et * 16 + l16] = acc[2][et][0];
        }
    }
    __syncthreads();
#pragma unroll
    for (int k = 0; k < 5; k++) {
        const int idx = t + k * 256;
        if (idx < 1056) {
            const int a = (idx >> 5) * 33 + (idx & 31);
            kvs[idx] = kvred[0][a] + kvred[1][a] + kvred[2][a] + kvred[3][a];
        }
    }
    __syncthreads();

    // phase 2: out = kv · relu(Q), K=32
    bf16x8 a0, a1, a2;
#pragma unroll
    for (int j = 0; j < 8; j++) {
        a0[j] = (short)f2bf(kvs[l16 * 32 + ko + j]);
        a1[j] = (short)f2bf(kvs[(16 + l16) * 32 + ko + j]);
        a2[j] = (l16 == 0) ? (short)f2bf(kvs[32 * 32 + ko + j]) : (short)0;
    }
    bf16x8 bfr[16];
    const unsigned short* qb = qp + (size_t)ko * NPIX + nb + l16;
#pragma unroll
    for (int tl = 0; tl < 16; tl++) {
        bf16x8 bf;
#pragma unroll
        for (int j = 0; j < 8; j++) {
            const unsigned short v = qb[(size_t)j * NPIX + tl * 16];
            bf[j] = (v & 0x8000u) ? (short)0 : (short)v;
        }
        bfr[tl] = bf;
    }
#pragma unroll
    for (int tl = 0; tl < 16; tl++) {
        f32x4 z = {0.f, 0.f, 0.f, 0.f};
        z = __builtin_amdgcn_mfma_f32_16x16x32_bf16(a2, bfr[tl], z, 0, 0, 0);
        if (lq == 0) dlds[w][tl * 16 + l16] = z[0];
    }
    __syncthreads();
#pragma unroll
    for (int tl = 0; tl < 16; tl++) {
        f32x4 c0 = {0.f, 0.f, 0.f, 0.f};
        f32x4 c1 = {0.f, 0.f, 0.f, 0.f};
        c0 = __builtin_amdgcn_mfma_f32_16x16x32_bf16(a0, bfr[tl], c0, 0, 0, 0);
        c1 = __builtin_amdgcn_mfma_f32_16x16x32_bf16(a1, bfr[tl], c1, 0, 0, 0);
        const float inv = 1.f / (dlds[w][tl * 16 + l16] + 1e-15f);
        u16x4 p0, p1;
#pragma unroll
        for (int r = 0; r < 4; r++) {
            p0[r] = f2bf(c0[r] * inv);
            p1[r] = f2bf(c1[r] * inv);
        }
        unsigned short* tp = &T[w][(tl * 16 + l16) * 40];
        *(u16x4*)(tp + lq * 4)      = p0;
        *(u16x4*)(tp + 16 + lq * 4) = p1;
    }
    __syncthreads();
#pragma unroll
    for (int k = 0; k < 16; k++) {
        const int idx = k * 64 + lane;
        const int db  = idx >> 8;
        const int px  = idx & 255;
        const u16x8 v = *(const u16x8*)(&T[w][px * 40 + db * 8]);
        *(u16x8*)(att + (((size_t)(b * 64 + h * 4 + db)) * NPIX + nb + px) * 8) = v;
    }
}

// ---------------------------------------------------------------------------
extern "C" void kernel_launch(void* const* d_in, const int* in_sizes, int n_in,
                              void* d_out, int out_size, void* d_ws, size_t ws_size,
                              hipStream_t stream)
{
    (void)in_sizes; (void)n_in; (void)out_size;

    const float* x      = (const float*)d_in[0];
    const float* y      = (const float*)d_in[1];
    const float* qkv_w  = (const float*)d_in[2];
    const float* dw5_w  = (const float*)d_in[3];
    const float* pwg_w  = (const float*)d_in[4];
    const float* proj_w = (const float*)d_in[5];
    const float* proj_g = (const float*)d_in[6];
    const float* proj_b = (const float*)d_in[7];
    const float* proj_m = (const float*)d_in[8];
    const float* proj_v = (const float*)d_in[9];
    const float* inv_w  = (const float*)d_in[10];
    const float* inv_b  = (const float*)d_in[11];
    const float* dwc_w  = (const float*)d_in[12];
    const float* dwc_b  = (const float*)d_in[13];
    const float* pw_w   = (const float*)d_in[14];
    const float* pw_g   = (const float*)d_in[15];
    const float* pw_b   = (const float*)d_in[16];
    const float* pw_m   = (const float*)d_in[17];
    const float* pw_v   = (const float*)d_in[18];

    float* ws = (float*)d_ws;
    unsigned short* wqkv_b  = (unsigned short*)(ws + WQKV_OFF);
    unsigned short* wproj_b = (unsigned short*)(ws + WPROJ_OFF);
    unsigned short* winv_b  = (unsigned short*)(ws + WINV_OFF);
    unsigned short* wpw_b   = (unsigned short*)(ws + WPW_OFF);
    float* out = (float*)d_out;

    wconv_all<<<dim3(416), 256, 0, stream>>>(qkv_w, proj_w, inv_w, pw_w,
                                             wqkv_b, wproj_b, winv_b, wpw_b);

    if (ws_size >= (size_t)BATCH_NEED_F * 4ull) {
        // ---------------- batched path: both chains as images 0..31 ----------
        unsigned short* bxt  = (unsigned short*)(ws + BXT_OFF);
        unsigned short* bqkv = (unsigned short*)(ws + BQKV_OFF);
        unsigned short* bdpw = (unsigned short*)(ws + BDPW_OFF);
        unsigned short* batt = (unsigned short*)(ws + BATT_OFF);
        unsigned short* bt1t = (unsigned short*)(ws + BT1T_OFF);
        unsigned short* bh1t = (unsigned short*)(ws + BH1T_OFF);
        unsigned short* bh2t = (unsigned short*)(ws + BH2T_OFF);

        xpose2<<<dim3(4096), 256, 0, stream>>>(x, y, bxt, 256);
        gemm_direct<128, 128, 0, false, 1><<<dim3(6, 256), 256, 0, stream>>>(
            bxt, nullptr, wqkv_b, nullptr, bqkv, 768, 256,
            nullptr, nullptr, nullptr, nullptr, nullptr, nullptr, nullptr, nullptr);
        dwconv5x5_v3<<<dim3(12288), 256, 0, stream>>>(bqkv, dw5_w, bdpw);
        grouped_pw<<<dim3(3072), 256, 0, stream>>>(bdpw, pwg_w);
        attn_fused<<<dim3(512), 256, 0, stream>>>(bqkv, bdpw, batt);
        gemm_direct<64, 64, 1, false, 2><<<dim3(4, 512), 256, 0, stream>>>(
            batt, nullptr, wproj_b, nullptr, bt1t, 256, 512,
            x, y, nullptr, proj_g, proj_b, proj_m, proj_v, nullptr);
        gemm_direct<128, 128, 2, false, 2><<<dim3(8, 256), 256, 0, stream>>>(
            bt1t, nullptr, winv_b, nullptr, bh1t, 1024, 256,
            nullptr, nullptr, nullptr, nullptr, nullptr, nullptr, nullptr, inv_b);
        dwconv3x3_blk<<<dim3(4096), 256, 0, stream>>>(bh1t, dwc_w, dwc_b, bh2t);
        gemm_direct<64, 64, 3, false, 0><<<dim3(4, 256), 256, 0, stream>>>(
            bh2t, bh2t + (size_t)16 * 1024 * 1024, wpw_b, out, nullptr, 256, 1024,
            nullptr, nullptr, bt1t, pw_g, pw_b, pw_m, pw_v, nullptr);
    } else {
        // ---------------- fallback: per-chain (R14 structure) ----------------
        unsigned short* wxt  = (unsigned short*)(ws + XT_OFF);
        unsigned short* wqkv = (unsigned short*)(ws + QKV_OFF);
        unsigned short* wdpw = (unsigned short*)(ws + DPW_OFF);
        unsigned short* watt = (unsigned short*)(ws + ATT_OFF);
        float*          wt1  = ws + T1_OFF;
        unsigned short* wt1t = (unsigned short*)(ws + T1T_OFF);
        unsigned short* wh1t = (unsigned short*)(ws + H1T_OFF);
        unsigned short* wh2t = (unsigned short*)(ws + H2T_OFF);

        for (int blk = 0; blk < 2; blk++) {
            const float* t = (blk == 0) ? x : y;
            xpose2<<<dim3(2048), 256, 0, stream>>>(t, t, wxt, 256);
            gemm_direct<128, 128, 0, false, 1><<<dim3(6, 128), 256, 0, stream>>>(
                wxt, nullptr, wqkv_b, nullptr, wqkv, 768, 256,
                nullptr, nullptr, nullptr, nullptr, nullptr, nullptr, nullptr, nullptr);
            dwconv5x5_v3<<<dim3(6144), 256, 0, stream>>>(wqkv, dw5_w, wdpw);
            grouped_pw<<<dim3(1536), 256, 0, stream>>>(wdpw, pwg_w);
            attn_fused<<<dim3(256), 256, 0, stream>>>(wqkv, wdpw, watt);
            gemm_direct<64, 64, 1, false, 3><<<dim3(4, 256), 256, 0, stream>>>(
                watt, watt, wproj_b, wt1, wt1t, 256, 512,
                t, t, nullptr, proj_g, proj_b, proj_m, proj_v, nullptr);
            gemm_direct<128, 128, 2, false, 2><<<dim3(8, 128), 256, 0, stream>>>(
                wt1t, nullptr, winv_b, nullptr, wh1t, 1024, 256,
                nullptr, nullptr, nullptr, nullptr, nullptr, nullptr, nullptr, inv_b);
            dwconv3x3_blk<<<dim3(2048), 256, 0, stream>>>(wh1t, dwc_w, dwc_b, wh2t);
            if (blk == 0) {
                gemm_direct<64, 64, 1, false, 0><<<dim3(4, 256), 256, 0, stream>>>(
                    wh2t, nullptr, wpw_b, out, nullptr, 256, 1024,
                    wt1, wt1, nullptr, pw_g, pw_b, pw_m, pw_v, nullptr);
            } else {
                gemm_direct<64, 64, 1, true, 0><<<dim3(4, 256), 256, 0, stream>>>(
                    wh2t, nullptr, wpw_b, out, nullptr, 256, 1024,
                    wt1, wt1, nullptr, pw_g, pw_b, pw_m, pw_v, nullptr);
            }
        }
    }
}